// Round 1
// 6770.275 us; speedup vs baseline: 1.8957x; 1.8957x over previous
//
#include <hip/hip_runtime.h>
#include <math.h>

// ---------------- helpers ----------------
__device__ __forceinline__ float block_reduce(float v, float* red) {
  int tid = threadIdx.x;
  red[tid] = v; __syncthreads();
  for (int s = 128; s >= 1; s >>= 1) {
    if (tid < s) red[tid] += red[tid + s];
    __syncthreads();
  }
  float r = red[0];
  __syncthreads();
  return r;
}

__global__ __launch_bounds__(256) void sentinel_kernel(float* __restrict__ out, int n, float v) {
  int i = blockIdx.x * 256 + threadIdx.x;
  if (i < n) out[i] = v;
}

// ---------------- BatchNorm stats ----------------
__global__ __launch_bounds__(256) void bn_stats_kernel(
    const float* __restrict__ tok, const float* __restrict__ g,
    const float* __restrict__ bb, float* __restrict__ ss) {
  __shared__ float red[256];
  const int d = blockIdx.x;
  float sum = 0.f, sumsq = 0.f;
  for (int s = threadIdx.x; s < 4096; s += 256) {
    float v = tok[s * 64 + d];
    sum += v; sumsq += v * v;
  }
  sum = block_reduce(sum, red);
  sumsq = block_reduce(sumsq, red);
  if (threadIdx.x == 0) {
    float mu = sum * (1.f / 4096.f);
    float var = sumsq * (1.f / 4096.f) - mu * mu;
    float sc = g[d] * rsqrtf(fmaxf(var, 0.f) + 1e-5f);
    ss[d] = sc;
    ss[64 + d] = bb[d] - mu * sc;
  }
}

__global__ __launch_bounds__(256) void tn_kernel(
    const float* __restrict__ tok, const float* __restrict__ ss,
    float* __restrict__ tn) {
  int idx = blockIdx.x * 256 + threadIdx.x;
  int d = idx & 63;
  tn[idx] = tok[idx] * ss[d] + ss[64 + d];
}

__global__ __launch_bounds__(256) void reverse_kernel(
    const float* __restrict__ x0, float* __restrict__ x0r) {
  int idx = blockIdx.x * 256 + threadIdx.x;
  int row = idx >> 9, e = idx & 511;
  int b = row >> 10, t = row & 1023;
  x0r[idx] = x0[((size_t)((b << 10) + (1023 - t))) * 512 + e];
}

// ---------------- row LayerNorm (N = 512 or 256) ----------------
__global__ __launch_bounds__(256) void ln_kernel(
    const float* __restrict__ x, const float* __restrict__ g,
    const float* __restrict__ b, float* __restrict__ out, int N) {
  __shared__ float red[256];
  const size_t r = blockIdx.x;
  const int tid = threadIdx.x;
  float v0 = x[r * N + tid];
  float v1 = (N > 256) ? x[r * N + 256 + tid] : 0.f;
  float sum = block_reduce(v0 + v1, red);
  float sumsq = block_reduce(v0 * v0 + v1 * v1, red);
  float mean = sum / (float)N;
  float var = sumsq / (float)N - mean * mean;
  float rs = rsqrtf(fmaxf(var, 0.f) + 1e-5f);
  out[r * N + tid] = (v0 - mean) * rs * g[tid] + b[tid];
  if (N > 256)
    out[r * N + 256 + tid] = (v1 - mean) * rs * g[256 + tid] + b[256 + tid];
}

// --------- GEMM (f32, float4-vectorized): out[M,N] = A@W + bias (+resid)(act) ---------
#define BK 16
template <int ACT>  // 0 none, 1 gelu(exact), 2 tanh
__global__ __launch_bounds__(256) void gemm3(
    const float* __restrict__ A, const float* __restrict__ W,
    const float* __restrict__ bias, const float* resid,
    float* out, int M, int N, int K) {
  __shared__ float As[BK][64 + 4];
  __shared__ float Bs[BK][64 + 4];
  const int tid = threadIdx.x;
  const int tx = tid & 15, ty = tid >> 4;
  const int n0 = blockIdx.x * 64, m0 = blockIdx.y * 64;
  float acc[4][4] = {};
  for (int k0 = 0; k0 < K; k0 += BK) {
    {  // A tile: 64 rows x 16 k, 256 float4 loads
      int m = tid >> 2, kq = tid & 3;
      float4 a4 = *reinterpret_cast<const float4*>(A + (size_t)(m0 + m) * K + k0 + kq * 4);
      As[kq * 4 + 0][m] = a4.x; As[kq * 4 + 1][m] = a4.y;
      As[kq * 4 + 2][m] = a4.z; As[kq * 4 + 3][m] = a4.w;
    }
    {  // B tile: 16 k x 64 n, 256 float4 loads
      int kk = tid >> 4, nq = tid & 15;
      float4 b4 = *reinterpret_cast<const float4*>(W + (size_t)(k0 + kk) * N + n0 + nq * 4);
      Bs[kk][nq * 4 + 0] = b4.x; Bs[kk][nq * 4 + 1] = b4.y;
      Bs[kk][nq * 4 + 2] = b4.z; Bs[kk][nq * 4 + 3] = b4.w;
    }
    __syncthreads();
#pragma unroll
    for (int kq = 0; kq < BK; ++kq) {
      float4 av = *reinterpret_cast<const float4*>(&As[kq][ty * 4]);
      float4 bv = *reinterpret_cast<const float4*>(&Bs[kq][tx * 4]);
      acc[0][0] += av.x * bv.x; acc[0][1] += av.x * bv.y; acc[0][2] += av.x * bv.z; acc[0][3] += av.x * bv.w;
      acc[1][0] += av.y * bv.x; acc[1][1] += av.y * bv.y; acc[1][2] += av.y * bv.z; acc[1][3] += av.y * bv.w;
      acc[2][0] += av.z * bv.x; acc[2][1] += av.z * bv.y; acc[2][2] += av.z * bv.z; acc[2][3] += av.z * bv.w;
      acc[3][0] += av.w * bv.x; acc[3][1] += av.w * bv.y; acc[3][2] += av.w * bv.z; acc[3][3] += av.w * bv.w;
    }
    __syncthreads();
  }
#pragma unroll
  for (int i = 0; i < 4; ++i) {
    int m = m0 + ty * 4 + i;
#pragma unroll
    for (int j = 0; j < 4; ++j) {
      int n = n0 + tx * 4 + j;
      float v = acc[i][j] + bias[n];
      if (resid) v += resid[(size_t)m * N + n];
      if (ACT == 1) v = 0.5f * v * (1.f + erff(v * 0.70710678118654752f));
      if (ACT == 2) v = tanhf(v);
      out[(size_t)m * N + n] = v;
    }
  }
}

// ---------------- attention: flash-style 64x64 tiles ----------------
// One block per (b, h, 64-query tile). Q^T staged once (pre-scaled); loop over
// causal key tiles: stage K^T + V, S = Q K^T as register-tiled GEMM (4x4/thread),
// online softmax via 16-lane shfl reductions, P^T written over the dead K tile,
// PV as second register-tiled GEMM. Block-causal mask is free for kt<qt and a
// frame compare on the diagonal tile. blockIdx remapped so blocks c and c+256
// (same CU under round-robin dispatch) get complementary qt / 15-qt tiles:
// constant 17 tile-steps per CU.
__global__ __launch_bounds__(256, 3) void attn_flash(
    const float* __restrict__ q, const float* __restrict__ k,
    const float* __restrict__ v, const float* __restrict__ mask,
    float* __restrict__ y, int rev) {
  __shared__ float Qt[64][68];  // [d][i], pre-scaled by 1/8
  __shared__ float KP[64][68];  // [d][j] for K^T; reused as P^T [j][i]
  __shared__ float Vs[64][68];  // [j][d]
  __shared__ float km[64];
  const int tid = threadIdx.x;
  const int tx = tid & 15, ty = tid >> 4;

  const int id = blockIdx.x;          // 0..511
  const int top = id >> 8;            // complementary-pair mapping
  const int r5 = id & 255;
  const int qt = top ? (15 - (r5 >> 4)) : (r5 >> 4);
  const int bh = (r5 & 15) | (top << 4);
  const int b = bh >> 3, h = bh & 7;

  {  // stage Q^T (scaled)
    const float* qp = q + (size_t)(b * 1024 + qt * 64) * 512 + h * 64;
#pragma unroll
    for (int r = 0; r < 4; ++r) {
      int f4 = r * 256 + tid;
      int row = f4 >> 4, dq = f4 & 15;
      float4 a = *reinterpret_cast<const float4*>(qp + (size_t)row * 512 + dq * 4);
      Qt[dq * 4 + 0][row] = a.x * 0.125f;
      Qt[dq * 4 + 1][row] = a.y * 0.125f;
      Qt[dq * 4 + 2][row] = a.z * 0.125f;
      Qt[dq * 4 + 3][row] = a.w * 0.125f;
    }
  }

  float m_[4], l_[4] = {0.f, 0.f, 0.f, 0.f};
  float o_[4][4] = {};
#pragma unroll
  for (int ii = 0; ii < 4; ++ii) m_[ii] = -1e30f;

  for (int kt = 0; kt <= qt; ++kt) {
    // ---- stage K^T, V, key-mask ----
    const float* kp = k + (size_t)(b * 1024 + kt * 64) * 512 + h * 64;
    const float* vp = v + (size_t)(b * 1024 + kt * 64) * 512 + h * 64;
#pragma unroll
    for (int r = 0; r < 4; ++r) {
      int f4 = r * 256 + tid;
      int row = f4 >> 4, dq = f4 & 15;
      float4 a = *reinterpret_cast<const float4*>(kp + (size_t)row * 512 + dq * 4);
      KP[dq * 4 + 0][row] = a.x;
      KP[dq * 4 + 1][row] = a.y;
      KP[dq * 4 + 2][row] = a.z;
      KP[dq * 4 + 3][row] = a.w;
      float4 vv4 = *reinterpret_cast<const float4*>(vp + (size_t)row * 512 + dq * 4);
      *reinterpret_cast<float4*>(&Vs[row][dq * 4]) = vv4;
    }
    if (tid < 64) {
      int s = kt * 64 + tid;
      int sidx = rev ? (1023 - s) : s;
      km[tid] = mask[b * 1024 + sidx];
    }
    __syncthreads();

    // ---- S = Q K^T (register 4x4 tile) ----
    float s_[4][4] = {};
#pragma unroll 4
    for (int d = 0; d < 64; ++d) {
      float4 av = *reinterpret_cast<const float4*>(&Qt[d][ty * 4]);
      float4 bv = *reinterpret_cast<const float4*>(&KP[d][tx * 4]);
      s_[0][0] += av.x * bv.x; s_[0][1] += av.x * bv.y; s_[0][2] += av.x * bv.z; s_[0][3] += av.x * bv.w;
      s_[1][0] += av.y * bv.x; s_[1][1] += av.y * bv.y; s_[1][2] += av.y * bv.z; s_[1][3] += av.y * bv.w;
      s_[2][0] += av.z * bv.x; s_[2][1] += av.z * bv.y; s_[2][2] += av.z * bv.z; s_[2][3] += av.z * bv.w;
      s_[3][0] += av.w * bv.x; s_[3][1] += av.w * bv.y; s_[3][2] += av.w * bv.z; s_[3][3] += av.w * bv.w;
    }
    __syncthreads();  // all threads done reading K tile

    // ---- mask + online softmax ----
    float kmv[4]; int jf[4];
#pragma unroll
    for (int jj = 0; jj < 4; ++jj) {
      int j = tx * 4 + jj;
      kmv[jj] = km[j];
      jf[jj] = j >> 3;
    }
#pragma unroll
    for (int ii = 0; ii < 4; ++ii) {
      int fi = (ty * 4 + ii) >> 3;
      float mt = -1e30f;
#pragma unroll
      for (int jj = 0; jj < 4; ++jj) {
        bool ok = (kmv[jj] > 0.f) && ((kt < qt) || (jf[jj] <= fi));
        float sv = ok ? s_[ii][jj] : -1e30f;
        s_[ii][jj] = sv;
        mt = fmaxf(mt, sv);
      }
      mt = fmaxf(mt, __shfl_xor(mt, 8, 16));
      mt = fmaxf(mt, __shfl_xor(mt, 4, 16));
      mt = fmaxf(mt, __shfl_xor(mt, 2, 16));
      mt = fmaxf(mt, __shfl_xor(mt, 1, 16));
      float mn = fmaxf(m_[ii], mt);
      float al = __expf(m_[ii] - mn);
      m_[ii] = mn;
      float rs = 0.f;
#pragma unroll
      for (int jj = 0; jj < 4; ++jj) {
        float sv = s_[ii][jj];
        float p = (sv > -1e29f) ? __expf(sv - mn) : 0.f;
        s_[ii][jj] = p;
        rs += p;
      }
      rs += __shfl_xor(rs, 8, 16);
      rs += __shfl_xor(rs, 4, 16);
      rs += __shfl_xor(rs, 2, 16);
      rs += __shfl_xor(rs, 1, 16);
      l_[ii] = l_[ii] * al + rs;
#pragma unroll
      for (int dd = 0; dd < 4; ++dd) o_[ii][dd] *= al;
    }

    // ---- write P^T over the dead K tile ----
#pragma unroll
    for (int jj = 0; jj < 4; ++jj) {
      float4 pv4 = make_float4(s_[0][jj], s_[1][jj], s_[2][jj], s_[3][jj]);
      *reinterpret_cast<float4*>(&KP[tx * 4 + jj][ty * 4]) = pv4;
    }
    __syncthreads();  // P visible

    // ---- O += P V (register 4x4 tile) ----
#pragma unroll 4
    for (int j = 0; j < 64; ++j) {
      float4 pa = *reinterpret_cast<const float4*>(&KP[j][ty * 4]);
      float4 vb = *reinterpret_cast<const float4*>(&Vs[j][tx * 4]);
      o_[0][0] += pa.x * vb.x; o_[0][1] += pa.x * vb.y; o_[0][2] += pa.x * vb.z; o_[0][3] += pa.x * vb.w;
      o_[1][0] += pa.y * vb.x; o_[1][1] += pa.y * vb.y; o_[1][2] += pa.y * vb.z; o_[1][3] += pa.y * vb.w;
      o_[2][0] += pa.z * vb.x; o_[2][1] += pa.z * vb.y; o_[2][2] += pa.z * vb.z; o_[2][3] += pa.z * vb.w;
      o_[3][0] += pa.w * vb.x; o_[3][1] += pa.w * vb.y; o_[3][2] += pa.w * vb.z; o_[3][3] += pa.w * vb.w;
    }
    __syncthreads();  // done reading KP/Vs before next staging
  }

  // ---- normalize + write ----
#pragma unroll
  for (int ii = 0; ii < 4; ++ii) {
    float inv = 1.f / fmaxf(l_[ii], 1e-30f);
    float4 ov = make_float4(o_[ii][0] * inv, o_[ii][1] * inv,
                            o_[ii][2] * inv, o_[ii][3] * inv);
    *reinterpret_cast<float4*>(
        y + (size_t)(b * 1024 + qt * 64 + ty * 4 + ii) * 512 + h * 64 + tx * 4) = ov;
  }
}

// ---------------- frame mean (+ FLOAT32 output write) ----------------
__global__ __launch_bounds__(256) void frame_mean_kernel(
    const float* __restrict__ xo, float* __restrict__ xf,
    float* __restrict__ outf) {
  int row = blockIdx.x;       // b*128+tf
  int o = threadIdx.x;
  float s = 0.f;
#pragma unroll
  for (int c = 0; c < 8; ++c) s += xo[((size_t)row * 8 + c) * 256 + o];
  s *= 0.125f;
  xf[row * 256 + o] = s;
  if (outf) outf[row * 256 + o] = s;
}

// ---------------- losses ----------------
__global__ __launch_bounds__(256) void loss_reg_kernel(
    const float* __restrict__ pd, const float* __restrict__ tok,
    const float* __restrict__ mask, float* __restrict__ acc, int rev) {
  __shared__ float red[256];
  float local = 0.f;
  for (int idx = blockIdx.x * 256 + threadIdx.x; idx < 260096; idx += gridDim.x * 256) {
    int b = idx / 65024, r2 = idx % 65024;
    int t = r2 >> 6, d = r2 & 63;
    float pred = pd[((size_t)((b << 10) + t)) * 64 + d] * mask[(b << 10) + t];
    int tt = rev ? (1015 - t) : (t + 8);
    float tgt = tok[((size_t)((b << 10) + tt)) * 64 + d] * mask[(b << 10) + tt];
    float df = pred - tgt;
    local += df * df;
  }
  float s = block_reduce(local, red);
  if (threadIdx.x == 0) atomicAdd(acc, s);
}

__global__ __launch_bounds__(256) void loss_fr_kernel(
    const float* __restrict__ pf, const float* __restrict__ tok,
    const float* __restrict__ mask, float* __restrict__ acc, int rev) {
  __shared__ float red[256];
  float local = 0.f;
  for (int idx = blockIdx.x * 256 + threadIdx.x; idx < 260096; idx += gridDim.x * 256) {
    int b = idx / 65024, r2 = idx % 65024;
    int i = r2 >> 9, u = r2 & 511;
    float pred = pf[((size_t)(b * 128 + i)) * 512 + u];
    int c = u >> 6;
    int t = rev ? ((126 - i) * 8 + c) : ((i + 1) * 8 + c);
    float tgt = tok[((size_t)((b << 10) + t)) * 64 + (u & 63)] * mask[(b << 10) + t];
    float df = pred - tgt;
    local += df * df;
  }
  float s = block_reduce(local, red);
  if (threadIdx.x == 0) atomicAdd(acc, s);
}

__global__ void finalize_kernel(const float* __restrict__ acc, float* __restrict__ out) {
  int i = threadIdx.x;
  if (i < 4) out[131072 + i] = acc[i] * (1.0f / 260096.0f);
}

extern "C" void kernel_launch(void* const* d_in, const int* in_sizes, int n_in,
                              void* d_out, int out_size, void* d_ws, size_t ws_size,
                              hipStream_t stream) {
  float* ws = (float*)d_ws;
  const size_t OFF_SS   = 0;
  const size_t OFF_LACC = 128;
  const size_t OFF_TN   = 256;
  const size_t OFF_X0   = OFF_TN + 262144;
  const size_t OFF_X0R  = OFF_X0 + 2097152;
  const size_t OFF_X    = OFF_X0R + 2097152;
  const size_t OFF_H    = OFF_X + 2097152;
  const size_t OFF_QKVY = OFF_H + 2097152;
  const size_t OFF_XO   = OFF_QKVY + 8388608;
  const size_t OFF_HD   = OFF_XO + 1048576;
  const size_t OFF_HD2  = OFF_HD + 1048576;
  const size_t OFF_PD   = OFF_HD2 + 1048576;
  const size_t OFF_XF   = OFF_PD + 262144;
  const size_t OFF_HF   = OFF_XF + 131072;
  const size_t OFF_HF2  = OFF_HF + 131072;
  const size_t OFF_PF   = OFF_HF2 + 131072;
  const size_t TOTAL    = OFF_PF + 262144;

  float* ss   = ws + OFF_SS;
  float* lacc = ws + OFF_LACC;
  float* tn   = ws + OFF_TN;
  float* x0   = ws + OFF_X0;
  float* x0r  = ws + OFF_X0R;
  float* x    = ws + OFF_X;
  float* h    = ws + OFF_H;
  float* q    = ws + OFF_QKVY;
  float* kk   = ws + OFF_QKVY + 2097152;
  float* vv   = ws + OFF_QKVY + 4194304;
  float* yb   = ws + OFF_QKVY + 6291456;
  float* u    = ws + OFF_QKVY;  // alias (MLP phase only)
  float* xo   = ws + OFF_XO;
  float* hd   = ws + OFF_HD;
  float* hd2  = ws + OFF_HD2;
  float* pd   = ws + OFF_PD;
  float* xf   = ws + OFF_XF;
  float* hf   = ws + OFF_HF;
  float* hf2  = ws + OFF_HF2;
  float* pf   = ws + OFF_PF;
  float* out_f = (float*)d_out;   // OUTPUT IS FLOAT32

  static const int EXPECTED[39] = {
      262144, 4096, 4096, 64, 64, 32768, 512, 3072, 3072, 3072, 3072,
      1572864, 3072, 1572864, 3072, 1572864, 3072, 1572864, 3072,
      6291456, 12288, 6291456, 3072, 512, 512, 131072, 256, 65536, 256,
      256, 256, 16384, 64, 65536, 256, 256, 256, 131072, 512};
  bool manifest_ok = (n_in == 39) && (ws_size >= TOTAL * sizeof(float));
  if (manifest_ok)
    for (int i = 0; i < 39; ++i)
      if (in_sizes[i] != EXPECTED[i]) { manifest_ok = false; break; }
  if (!manifest_ok) {
    hipLaunchKernelGGL(sentinel_kernel, dim3((out_size + 255) / 256), dim3(256), 0, stream,
                       out_f, out_size, 2000.0f);
    return;
  }

  const float* tok    = (const float*)d_in[0];
  const float* mask   = (const float*)d_in[2];
  const float* bn_g   = (const float*)d_in[3];
  const float* bn_b   = (const float*)d_in[4];
  const float* We     = (const float*)d_in[5];
  const float* be     = (const float*)d_in[6];
  const float* ln1_g  = (const float*)d_in[7];
  const float* ln1_b  = (const float*)d_in[8];
  const float* ln2_g  = (const float*)d_in[9];
  const float* ln2_b  = (const float*)d_in[10];
  const float* Wq     = (const float*)d_in[11];
  const float* bq     = (const float*)d_in[12];
  const float* Wk     = (const float*)d_in[13];
  const float* bk     = (const float*)d_in[14];
  const float* Wv     = (const float*)d_in[15];
  const float* bv     = (const float*)d_in[16];
  const float* Wo     = (const float*)d_in[17];
  const float* bo     = (const float*)d_in[18];
  const float* W1     = (const float*)d_in[19];
  const float* b1     = (const float*)d_in[20];
  const float* W2     = (const float*)d_in[21];
  const float* b2     = (const float*)d_in[22];
  const float* lnf_g  = (const float*)d_in[23];
  const float* lnf_b  = (const float*)d_in[24];
  const float* Wp     = (const float*)d_in[25];
  const float* bp     = (const float*)d_in[26];
  const float* Wd1    = (const float*)d_in[27];
  const float* bd1    = (const float*)d_in[28];
  const float* lnd_g  = (const float*)d_in[29];
  const float* lnd_b  = (const float*)d_in[30];
  const float* Wd2    = (const float*)d_in[31];
  const float* bd2    = (const float*)d_in[32];
  const float* Wf1    = (const float*)d_in[33];
  const float* bf1    = (const float*)d_in[34];
  const float* lnfr_g = (const float*)d_in[35];
  const float* lnfr_b = (const float*)d_in[36];
  const float* Wf2    = (const float*)d_in[37];
  const float* bf2    = (const float*)d_in[38];

  auto G = [&](int act, const float* A, const float* W, const float* bias,
               const float* resid, float* out, int M, int N, int K) {
    dim3 g(N / 64, M / 64), b(256);
    if (act == 0) hipLaunchKernelGGL((gemm3<0>), g, b, 0, stream, A, W, bias, resid, out, M, N, K);
    else if (act == 1) hipLaunchKernelGGL((gemm3<1>), g, b, 0, stream, A, W, bias, resid, out, M, N, K);
    else hipLaunchKernelGGL((gemm3<2>), g, b, 0, stream, A, W, bias, resid, out, M, N, K);
  };

  hipMemsetAsync(lacc, 0, 4 * sizeof(float), stream);
  hipLaunchKernelGGL(bn_stats_kernel, dim3(64), dim3(256), 0, stream, tok, bn_g, bn_b, ss);
  hipLaunchKernelGGL(tn_kernel, dim3(1024), dim3(256), 0, stream, tok, ss, tn);
  G(0, tn, We, be, nullptr, x0, 4096, 512, 64);
  hipLaunchKernelGGL(reverse_kernel, dim3(8192), dim3(256), 0, stream, x0, x0r);

  for (int dir = 0; dir < 2; ++dir) {
    const float* xin = dir ? x0r : x0;
    for (int l = 0; l < 6; ++l) {
      const float* xl = (l == 0) ? xin : x;
      hipLaunchKernelGGL(ln_kernel, dim3(4096), dim3(256), 0, stream,
                         xl, ln1_g + l * 512, ln1_b + l * 512, h, 512);
      G(0, h, Wq + (size_t)l * 262144, bq + l * 512, nullptr, q, 4096, 512, 512);
      G(0, h, Wk + (size_t)l * 262144, bk + l * 512, nullptr, kk, 4096, 512, 512);
      G(0, h, Wv + (size_t)l * 262144, bv + l * 512, nullptr, vv, 4096, 512, 512);
      hipLaunchKernelGGL(attn_flash, dim3(512), dim3(256), 0, stream,
                         q, kk, vv, mask, yb, dir);
      G(0, yb, Wo + (size_t)l * 262144, bo + l * 512, xl, x, 4096, 512, 512);
      hipLaunchKernelGGL(ln_kernel, dim3(4096), dim3(256), 0, stream,
                         x, ln2_g + l * 512, ln2_b + l * 512, h, 512);
      G(1, h, W1 + (size_t)l * 1048576, b1 + l * 2048, nullptr, u, 4096, 2048, 512);
      G(0, u, W2 + (size_t)l * 1048576, b2 + l * 512, x, x, 4096, 512, 2048);
    }
    hipLaunchKernelGGL(ln_kernel, dim3(4096), dim3(256), 0, stream, x, lnf_g, lnf_b, h, 512);
    G(0, h, Wp, bp, nullptr, xo, 4096, 256, 512);
    G(2, xo, Wd1, bd1, nullptr, hd, 4096, 256, 256);
    hipLaunchKernelGGL(ln_kernel, dim3(4096), dim3(256), 0, stream, hd, lnd_g, lnd_b, hd2, 256);
    G(0, hd2, Wd2, bd2, nullptr, pd, 4096, 64, 256);
    hipLaunchKernelGGL(loss_reg_kernel, dim3(256), dim3(256), 0, stream,
                       pd, tok, mask, lacc + (dir ? 1 : 0), dir);
    hipLaunchKernelGGL(frame_mean_kernel, dim3(512), dim3(256), 0, stream,
                       xo, xf, dir == 0 ? out_f : (float*)nullptr);
    G(2, xf, Wf1, bf1, nullptr, hf, 512, 256, 256);
    hipLaunchKernelGGL(ln_kernel, dim3(512), dim3(256), 0, stream, hf, lnfr_g, lnfr_b, hf2, 256);
    G(0, hf2, Wf2, bf2, nullptr, pf, 512, 512, 256);
    hipLaunchKernelGGL(loss_fr_kernel, dim3(256), dim3(256), 0, stream,
                       pf, tok, mask, lacc + (dir ? 3 : 2), dir);
  }
  hipLaunchKernelGGL(finalize_kernel, dim3(1), dim3(64), 0, stream, lacc, out_f);
}

// Round 2
// 4213.063 us; speedup vs baseline: 3.0463x; 1.6070x over previous
//
#include <hip/hip_runtime.h>
#include <math.h>

typedef short short8 __attribute__((ext_vector_type(8)));
typedef float f32x4 __attribute__((ext_vector_type(4)));

// ---------------- helpers ----------------
__device__ __forceinline__ float block_reduce(float v, float* red) {
  int tid = threadIdx.x;
  red[tid] = v; __syncthreads();
  for (int s = 128; s >= 1; s >>= 1) {
    if (tid < s) red[tid] += red[tid + s];
    __syncthreads();
  }
  float r = red[0];
  __syncthreads();
  return r;
}

// f32 -> (hi bf16, lo bf16) split, packed pairwise into uints (elem k in low 16).
// hi = round-half-up bf16 (2 ops); lo = x - hi exactly representable, truncated
// to bf16. Per-product relative error ~2^-17.
__device__ __forceinline__ void cvt2(float a, float b, unsigned& hp, unsigned& lp) {
  unsigned ua = __float_as_uint(a), ub = __float_as_uint(b);
  unsigned ha = (ua + 0x8000u) & 0xffff0000u;
  unsigned hb = (ub + 0x8000u) & 0xffff0000u;
  float la = a - __uint_as_float(ha);
  float lb = b - __uint_as_float(hb);
  hp = (ha >> 16) | hb;
  lp = (__float_as_uint(la) >> 16) | (__float_as_uint(lb) & 0xffff0000u);
}

__global__ __launch_bounds__(256) void sentinel_kernel(float* __restrict__ out, int n, float v) {
  int i = blockIdx.x * 256 + threadIdx.x;
  if (i < n) out[i] = v;
}

// ---------------- BatchNorm stats ----------------
__global__ __launch_bounds__(256) void bn_stats_kernel(
    const float* __restrict__ tok, const float* __restrict__ g,
    const float* __restrict__ bb, float* __restrict__ ss) {
  __shared__ float red[256];
  const int d = blockIdx.x;
  float sum = 0.f, sumsq = 0.f;
  for (int s = threadIdx.x; s < 4096; s += 256) {
    float v = tok[s * 64 + d];
    sum += v; sumsq += v * v;
  }
  sum = block_reduce(sum, red);
  sumsq = block_reduce(sumsq, red);
  if (threadIdx.x == 0) {
    float mu = sum * (1.f / 4096.f);
    float var = sumsq * (1.f / 4096.f) - mu * mu;
    float sc = g[d] * rsqrtf(fmaxf(var, 0.f) + 1e-5f);
    ss[d] = sc;
    ss[64 + d] = bb[d] - mu * sc;
  }
}

__global__ __launch_bounds__(256) void tn_kernel(
    const float* __restrict__ tok, const float* __restrict__ ss,
    float* __restrict__ tn) {
  int idx = blockIdx.x * 256 + threadIdx.x;
  int d = idx & 63;
  tn[idx] = tok[idx] * ss[d] + ss[64 + d];
}

__global__ __launch_bounds__(256) void reverse_kernel(
    const float* __restrict__ x0, float* __restrict__ x0r) {
  int idx = blockIdx.x * 256 + threadIdx.x;
  int row = idx >> 9, e = idx & 511;
  int b = row >> 10, t = row & 1023;
  x0r[idx] = x0[((size_t)((b << 10) + (1023 - t))) * 512 + e];
}

// ---------------- row LayerNorm (N = 512 or 256) ----------------
__global__ __launch_bounds__(256) void ln_kernel(
    const float* __restrict__ x, const float* __restrict__ g,
    const float* __restrict__ b, float* __restrict__ out, int N) {
  __shared__ float red[256];
  const size_t r = blockIdx.x;
  const int tid = threadIdx.x;
  float v0 = x[r * N + tid];
  float v1 = (N > 256) ? x[r * N + 256 + tid] : 0.f;
  float sum = block_reduce(v0 + v1, red);
  float sumsq = block_reduce(v0 * v0 + v1 * v1, red);
  float mean = sum / (float)N;
  float var = sumsq / (float)N - mean * mean;
  float rs = rsqrtf(fmaxf(var, 0.f) + 1e-5f);
  out[r * N + tid] = (v0 - mean) * rs * g[tid] + b[tid];
  if (N > 256)
    out[r * N + 256 + tid] = (v1 - mean) * rs * g[256 + tid] + b[256 + tid];
}

// --------- small GEMM (f32): out[M,N] = A@W + bias (+resid)(act) ---------
#define BK 16
template <int ACT>  // 0 none, 1 gelu(exact), 2 tanh
__global__ __launch_bounds__(256) void gemm3(
    const float* __restrict__ A, const float* __restrict__ W,
    const float* __restrict__ bias, const float* resid,
    float* out, int M, int N, int K) {
  __shared__ float As[BK][64 + 4];
  __shared__ float Bs[BK][64 + 4];
  const int tid = threadIdx.x;
  const int tx = tid & 15, ty = tid >> 4;
  const int n0 = blockIdx.x * 64, m0 = blockIdx.y * 64;
  float acc[4][4] = {};
  for (int k0 = 0; k0 < K; k0 += BK) {
    {
      int m = tid >> 2, kq = tid & 3;
      float4 a4 = *reinterpret_cast<const float4*>(A + (size_t)(m0 + m) * K + k0 + kq * 4);
      As[kq * 4 + 0][m] = a4.x; As[kq * 4 + 1][m] = a4.y;
      As[kq * 4 + 2][m] = a4.z; As[kq * 4 + 3][m] = a4.w;
    }
    {
      int kk = tid >> 4, nq = tid & 15;
      float4 b4 = *reinterpret_cast<const float4*>(W + (size_t)(k0 + kk) * N + n0 + nq * 4);
      Bs[kk][nq * 4 + 0] = b4.x; Bs[kk][nq * 4 + 1] = b4.y;
      Bs[kk][nq * 4 + 2] = b4.z; Bs[kk][nq * 4 + 3] = b4.w;
    }
    __syncthreads();
#pragma unroll
    for (int kq = 0; kq < BK; ++kq) {
      float4 av = *reinterpret_cast<const float4*>(&As[kq][ty * 4]);
      float4 bv = *reinterpret_cast<const float4*>(&Bs[kq][tx * 4]);
      acc[0][0] += av.x * bv.x; acc[0][1] += av.x * bv.y; acc[0][2] += av.x * bv.z; acc[0][3] += av.x * bv.w;
      acc[1][0] += av.y * bv.x; acc[1][1] += av.y * bv.y; acc[1][2] += av.y * bv.z; acc[1][3] += av.y * bv.w;
      acc[2][0] += av.z * bv.x; acc[2][1] += av.z * bv.y; acc[2][2] += av.z * bv.z; acc[2][3] += av.z * bv.w;
      acc[3][0] += av.w * bv.x; acc[3][1] += av.w * bv.y; acc[3][2] += av.w * bv.z; acc[3][3] += av.w * bv.w;
    }
    __syncthreads();
  }
#pragma unroll
  for (int i = 0; i < 4; ++i) {
    int m = m0 + ty * 4 + i;
#pragma unroll
    for (int j = 0; j < 4; ++j) {
      int n = n0 + tx * 4 + j;
      float v = acc[i][j] + bias[n];
      if (resid) v += resid[(size_t)m * N + n];
      if (ACT == 1) v = 0.5f * v * (1.f + erff(v * 0.70710678118654752f));
      if (ACT == 2) v = tanhf(v);
      out[(size_t)m * N + n] = v;
    }
  }
}

// --------- MFMA GEMM, fp32 via bf16x3 split. 128x128x32 tiles, 4 waves. ---------
// ACT: 0 none, 1 gelu.  ATOMIC: atomicAdd into C (C pre-holds resid; z==0 adds bias).
// FUSE3: blockIdx.x selects one of 3 weight/bias/out sections (QKV), each Nsec wide.
template <int ACT, int ATOMIC, int FUSE3>
__global__ __launch_bounds__(256, 2) void gemm_mfma(
    const float* __restrict__ A,
    const float* __restrict__ B0, const float* __restrict__ B1, const float* __restrict__ B2,
    const float* __restrict__ bias0, const float* __restrict__ bias1, const float* __restrict__ bias2,
    const float* __restrict__ resid,
    float* __restrict__ C0, float* __restrict__ C1, float* __restrict__ C2,
    int M, int Nsec, int K, int KZ) {
  // A tiles: [row 128][32 bf16 + pad] as 20 uints (80B rows, 16B-aligned).
  // B tiles: B^T [n 128][32 bf16], 16B k-slots XOR-swizzled by (n&3).
  __shared__ unsigned Ah[128][20];
  __shared__ unsigned Al[128][20];
  __shared__ unsigned Bh[128][20];
  __shared__ unsigned Bl[128][20];
  const int tid = threadIdx.x;
  const int lane = tid & 63, wid = tid >> 6;
  const int wr = wid >> 1, wc = wid & 1;
  const int lr = lane & 15, lq = lane >> 4;

  int nb = blockIdx.x, sec = 0;
  if (FUSE3) { sec = nb >> 2; nb &= 3; }
  const float* Bg = FUSE3 ? (sec == 0 ? B0 : (sec == 1 ? B1 : B2)) : B0;
  const float* bias = FUSE3 ? (sec == 0 ? bias0 : (sec == 1 ? bias1 : bias2)) : bias0;
  float* C = FUSE3 ? (sec == 0 ? C0 : (sec == 1 ? C1 : C2)) : C0;
  const int n0 = nb * 128;
  const int m0 = blockIdx.y * 128;
  const int kbase = blockIdx.z * KZ;

  f32x4 acc[4][4];
#pragma unroll
  for (int i = 0; i < 4; ++i)
#pragma unroll
    for (int j = 0; j < 4; ++j) { acc[i][j][0] = 0.f; acc[i][j][1] = 0.f; acc[i][j][2] = 0.f; acc[i][j][3] = 0.f; }

  const int nB = tid & 127;     // B-staging: this thread's output column
  const int khalf = tid >> 7;   // k-half (16 k each)

  for (int k0 = kbase; k0 < kbase + KZ; k0 += 32) {
    // ---- stage A (f32 -> hi/lo bf16) ----
#pragma unroll
    for (int i = 0; i < 4; ++i) {
      int idx = i * 256 + tid;
      int row = idx >> 3, c4 = idx & 7;
      float4 a4 = *reinterpret_cast<const float4*>(A + (size_t)(m0 + row) * K + k0 + c4 * 4);
      unsigned h0, l0, h1, l1;
      cvt2(a4.x, a4.y, h0, l0);
      cvt2(a4.z, a4.w, h1, l1);
      *reinterpret_cast<uint2*>(&Ah[row][c4 * 2]) = make_uint2(h0, h1);
      *reinterpret_cast<uint2*>(&Al[row][c4 * 2]) = make_uint2(l0, l1);
    }
    // ---- stage B^T (scalar k-strided loads, contiguous k writes) ----
    {
      const float* bp = Bg + (size_t)(k0 + khalf * 16) * Nsec + n0 + nB;
      float w[16];
#pragma unroll
      for (int r = 0; r < 16; ++r) w[r] = bp[(size_t)r * Nsec];
      unsigned hp[8], lp[8];
#pragma unroll
      for (int j = 0; j < 8; ++j) cvt2(w[2 * j], w[2 * j + 1], hp[j], lp[j]);
      int sw = nB & 3;
      int s0 = (khalf * 2) ^ sw, s1 = (khalf * 2 + 1) ^ sw;
      *reinterpret_cast<uint4*>(&Bh[nB][s0 * 4]) = make_uint4(hp[0], hp[1], hp[2], hp[3]);
      *reinterpret_cast<uint4*>(&Bh[nB][s1 * 4]) = make_uint4(hp[4], hp[5], hp[6], hp[7]);
      *reinterpret_cast<uint4*>(&Bl[nB][s0 * 4]) = make_uint4(lp[0], lp[1], lp[2], lp[3]);
      *reinterpret_cast<uint4*>(&Bl[nB][s1 * 4]) = make_uint4(lp[4], lp[5], lp[6], lp[7]);
    }
    __syncthreads();
    // ---- fragments + 48 MFMA ----
    short8 ah[4], al[4], bh[4], bl[4];
#pragma unroll
    for (int mi = 0; mi < 4; ++mi) {
      int row = wr * 64 + mi * 16 + lr;
      ah[mi] = *reinterpret_cast<const short8*>(&Ah[row][lq * 4]);
      al[mi] = *reinterpret_cast<const short8*>(&Al[row][lq * 4]);
    }
#pragma unroll
    for (int ni = 0; ni < 4; ++ni) {
      int n = wc * 64 + ni * 16 + lr;
      int sp = lq ^ (n & 3);
      bh[ni] = *reinterpret_cast<const short8*>(&Bh[n][sp * 4]);
      bl[ni] = *reinterpret_cast<const short8*>(&Bl[n][sp * 4]);
    }
#pragma unroll
    for (int mi = 0; mi < 4; ++mi)
#pragma unroll
      for (int ni = 0; ni < 4; ++ni) {
        acc[mi][ni] = __builtin_amdgcn_mfma_f32_16x16x32_bf16(ah[mi], bh[ni], acc[mi][ni], 0, 0, 0);
        acc[mi][ni] = __builtin_amdgcn_mfma_f32_16x16x32_bf16(ah[mi], bl[ni], acc[mi][ni], 0, 0, 0);
        acc[mi][ni] = __builtin_amdgcn_mfma_f32_16x16x32_bf16(al[mi], bh[ni], acc[mi][ni], 0, 0, 0);
      }
    __syncthreads();
  }

  // ---- epilogue ----
#pragma unroll
  for (int mi = 0; mi < 4; ++mi) {
#pragma unroll
    for (int r = 0; r < 4; ++r) {
      int grow = m0 + wr * 64 + mi * 16 + lq * 4 + r;
#pragma unroll
      for (int ni = 0; ni < 4; ++ni) {
        int col = wc * 64 + ni * 16 + lr;
        float v = acc[mi][ni][r];
        if (ATOMIC) {
          if (blockIdx.z == 0) v += bias[n0 + col];
          atomicAdd(&C[(size_t)grow * Nsec + n0 + col], v);
        } else {
          v += bias[n0 + col];
          if (resid) v += resid[(size_t)grow * Nsec + n0 + col];
          if (ACT == 1) v = 0.5f * v * (1.f + erff(v * 0.70710678118654752f));
          C[(size_t)grow * Nsec + n0 + col] = v;
        }
      }
    }
  }
}

// ---------------- attention: flash-style 64x64 tiles ----------------
__global__ __launch_bounds__(256, 3) void attn_flash(
    const float* __restrict__ q, const float* __restrict__ k,
    const float* __restrict__ v, const float* __restrict__ mask,
    float* __restrict__ y, int rev) {
  __shared__ float Qt[64][68];  // [d][i], pre-scaled by 1/8
  __shared__ float KP[64][68];  // [d][j] for K^T; reused as P^T [j][i]
  __shared__ float Vs[64][68];  // [j][d]
  __shared__ float km[64];
  const int tid = threadIdx.x;
  const int tx = tid & 15, ty = tid >> 4;

  const int id = blockIdx.x;          // 0..511
  const int top = id >> 8;            // complementary-pair mapping
  const int r5 = id & 255;
  const int qt = top ? (15 - (r5 >> 4)) : (r5 >> 4);
  const int bh = (r5 & 15) | (top << 4);
  const int b = bh >> 3, h = bh & 7;

  {  // stage Q^T (scaled)
    const float* qp = q + (size_t)(b * 1024 + qt * 64) * 512 + h * 64;
#pragma unroll
    for (int r = 0; r < 4; ++r) {
      int f4 = r * 256 + tid;
      int row = f4 >> 4, dq = f4 & 15;
      float4 a = *reinterpret_cast<const float4*>(qp + (size_t)row * 512 + dq * 4);
      Qt[dq * 4 + 0][row] = a.x * 0.125f;
      Qt[dq * 4 + 1][row] = a.y * 0.125f;
      Qt[dq * 4 + 2][row] = a.z * 0.125f;
      Qt[dq * 4 + 3][row] = a.w * 0.125f;
    }
  }

  float m_[4], l_[4] = {0.f, 0.f, 0.f, 0.f};
  float o_[4][4] = {};
#pragma unroll
  for (int ii = 0; ii < 4; ++ii) m_[ii] = -1e30f;

  for (int kt = 0; kt <= qt; ++kt) {
    const float* kp = k + (size_t)(b * 1024 + kt * 64) * 512 + h * 64;
    const float* vp = v + (size_t)(b * 1024 + kt * 64) * 512 + h * 64;
#pragma unroll
    for (int r = 0; r < 4; ++r) {
      int f4 = r * 256 + tid;
      int row = f4 >> 4, dq = f4 & 15;
      float4 a = *reinterpret_cast<const float4*>(kp + (size_t)row * 512 + dq * 4);
      KP[dq * 4 + 0][row] = a.x;
      KP[dq * 4 + 1][row] = a.y;
      KP[dq * 4 + 2][row] = a.z;
      KP[dq * 4 + 3][row] = a.w;
      float4 vv4 = *reinterpret_cast<const float4*>(vp + (size_t)row * 512 + dq * 4);
      *reinterpret_cast<float4*>(&Vs[row][dq * 4]) = vv4;
    }
    if (tid < 64) {
      int s = kt * 64 + tid;
      int sidx = rev ? (1023 - s) : s;
      km[tid] = mask[b * 1024 + sidx];
    }
    __syncthreads();

    float s_[4][4] = {};
#pragma unroll 4
    for (int d = 0; d < 64; ++d) {
      float4 av = *reinterpret_cast<const float4*>(&Qt[d][ty * 4]);
      float4 bv = *reinterpret_cast<const float4*>(&KP[d][tx * 4]);
      s_[0][0] += av.x * bv.x; s_[0][1] += av.x * bv.y; s_[0][2] += av.x * bv.z; s_[0][3] += av.x * bv.w;
      s_[1][0] += av.y * bv.x; s_[1][1] += av.y * bv.y; s_[1][2] += av.y * bv.z; s_[1][3] += av.y * bv.w;
      s_[2][0] += av.z * bv.x; s_[2][1] += av.z * bv.y; s_[2][2] += av.z * bv.z; s_[2][3] += av.z * bv.w;
      s_[3][0] += av.w * bv.x; s_[3][1] += av.w * bv.y; s_[3][2] += av.w * bv.z; s_[3][3] += av.w * bv.w;
    }
    __syncthreads();

    float kmv[4]; int jf[4];
#pragma unroll
    for (int jj = 0; jj < 4; ++jj) {
      int j = tx * 4 + jj;
      kmv[jj] = km[j];
      jf[jj] = j >> 3;
    }
#pragma unroll
    for (int ii = 0; ii < 4; ++ii) {
      int fi = (ty * 4 + ii) >> 3;
      float mt = -1e30f;
#pragma unroll
      for (int jj = 0; jj < 4; ++jj) {
        bool ok = (kmv[jj] > 0.f) && ((kt < qt) || (jf[jj] <= fi));
        float sv = ok ? s_[ii][jj] : -1e30f;
        s_[ii][jj] = sv;
        mt = fmaxf(mt, sv);
      }
      mt = fmaxf(mt, __shfl_xor(mt, 8, 16));
      mt = fmaxf(mt, __shfl_xor(mt, 4, 16));
      mt = fmaxf(mt, __shfl_xor(mt, 2, 16));
      mt = fmaxf(mt, __shfl_xor(mt, 1, 16));
      float mn = fmaxf(m_[ii], mt);
      float al = __expf(m_[ii] - mn);
      m_[ii] = mn;
      float rs = 0.f;
#pragma unroll
      for (int jj = 0; jj < 4; ++jj) {
        float sv = s_[ii][jj];
        float p = (sv > -1e29f) ? __expf(sv - mn) : 0.f;
        s_[ii][jj] = p;
        rs += p;
      }
      rs += __shfl_xor(rs, 8, 16);
      rs += __shfl_xor(rs, 4, 16);
      rs += __shfl_xor(rs, 2, 16);
      rs += __shfl_xor(rs, 1, 16);
      l_[ii] = l_[ii] * al + rs;
#pragma unroll
      for (int dd = 0; dd < 4; ++dd) o_[ii][dd] *= al;
    }

#pragma unroll
    for (int jj = 0; jj < 4; ++jj) {
      float4 pv4 = make_float4(s_[0][jj], s_[1][jj], s_[2][jj], s_[3][jj]);
      *reinterpret_cast<float4*>(&KP[tx * 4 + jj][ty * 4]) = pv4;
    }
    __syncthreads();

#pragma unroll 4
    for (int j = 0; j < 64; ++j) {
      float4 pa = *reinterpret_cast<const float4*>(&KP[j][ty * 4]);
      float4 vb = *reinterpret_cast<const float4*>(&Vs[j][tx * 4]);
      o_[0][0] += pa.x * vb.x; o_[0][1] += pa.x * vb.y; o_[0][2] += pa.x * vb.z; o_[0][3] += pa.x * vb.w;
      o_[1][0] += pa.y * vb.x; o_[1][1] += pa.y * vb.y; o_[1][2] += pa.y * vb.z; o_[1][3] += pa.y * vb.w;
      o_[2][0] += pa.z * vb.x; o_[2][1] += pa.z * vb.y; o_[2][2] += pa.z * vb.z; o_[2][3] += pa.z * vb.w;
      o_[3][0] += pa.w * vb.x; o_[3][1] += pa.w * vb.y; o_[3][2] += pa.w * vb.z; o_[3][3] += pa.w * vb.w;
    }
    __syncthreads();
  }

#pragma unroll
  for (int ii = 0; ii < 4; ++ii) {
    float inv = 1.f / fmaxf(l_[ii], 1e-30f);
    float4 ov = make_float4(o_[ii][0] * inv, o_[ii][1] * inv,
                            o_[ii][2] * inv, o_[ii][3] * inv);
    *reinterpret_cast<float4*>(
        y + (size_t)(b * 1024 + qt * 64 + ty * 4 + ii) * 512 + h * 64 + tx * 4) = ov;
  }
}

// ---------------- frame mean (+ FLOAT32 output write) ----------------
__global__ __launch_bounds__(256) void frame_mean_kernel(
    const float* __restrict__ xo, float* __restrict__ xf,
    float* __restrict__ outf) {
  int row = blockIdx.x;       // b*128+tf
  int o = threadIdx.x;
  float s = 0.f;
#pragma unroll
  for (int c = 0; c < 8; ++c) s += xo[((size_t)row * 8 + c) * 256 + o];
  s *= 0.125f;
  xf[row * 256 + o] = s;
  if (outf) outf[row * 256 + o] = s;
}

// ---------------- losses ----------------
__global__ __launch_bounds__(256) void loss_reg_kernel(
    const float* __restrict__ pd, const float* __restrict__ tok,
    const float* __restrict__ mask, float* __restrict__ acc, int rev) {
  __shared__ float red[256];
  float local = 0.f;
  for (int idx = blockIdx.x * 256 + threadIdx.x; idx < 260096; idx += gridDim.x * 256) {
    int b = idx / 65024, r2 = idx % 65024;
    int t = r2 >> 6, d = r2 & 63;
    float pred = pd[((size_t)((b << 10) + t)) * 64 + d] * mask[(b << 10) + t];
    int tt = rev ? (1015 - t) : (t + 8);
    float tgt = tok[((size_t)((b << 10) + tt)) * 64 + d] * mask[(b << 10) + tt];
    float df = pred - tgt;
    local += df * df;
  }
  float s = block_reduce(local, red);
  if (threadIdx.x == 0) atomicAdd(acc, s);
}

__global__ __launch_bounds__(256) void loss_fr_kernel(
    const float* __restrict__ pf, const float* __restrict__ tok,
    const float* __restrict__ mask, float* __restrict__ acc, int rev) {
  __shared__ float red[256];
  float local = 0.f;
  for (int idx = blockIdx.x * 256 + threadIdx.x; idx < 260096; idx += gridDim.x * 256) {
    int b = idx / 65024, r2 = idx % 65024;
    int i = r2 >> 9, u = r2 & 511;
    float pred = pf[((size_t)(b * 128 + i)) * 512 + u];
    int c = u >> 6;
    int t = rev ? ((126 - i) * 8 + c) : ((i + 1) * 8 + c);
    float tgt = tok[((size_t)((b << 10) + t)) * 64 + (u & 63)] * mask[(b << 10) + t];
    float df = pred - tgt;
    local += df * df;
  }
  float s = block_reduce(local, red);
  if (threadIdx.x == 0) atomicAdd(acc, s);
}

__global__ void finalize_kernel(const float* __restrict__ acc, float* __restrict__ out) {
  int i = threadIdx.x;
  if (i < 4) out[131072 + i] = acc[i] * (1.0f / 260096.0f);
}

extern "C" void kernel_launch(void* const* d_in, const int* in_sizes, int n_in,
                              void* d_out, int out_size, void* d_ws, size_t ws_size,
                              hipStream_t stream) {
  float* ws = (float*)d_ws;
  const size_t OFF_SS   = 0;
  const size_t OFF_LACC = 128;
  const size_t OFF_TN   = 256;
  const size_t OFF_X0   = OFF_TN + 262144;
  const size_t OFF_X0R  = OFF_X0 + 2097152;
  const size_t OFF_X    = OFF_X0R + 2097152;
  const size_t OFF_H    = OFF_X + 2097152;
  const size_t OFF_QKVY = OFF_H + 2097152;
  const size_t OFF_XO   = OFF_QKVY + 8388608;
  const size_t OFF_HD   = OFF_XO + 1048576;
  const size_t OFF_HD2  = OFF_HD + 1048576;
  const size_t OFF_PD   = OFF_HD2 + 1048576;
  const size_t OFF_XF   = OFF_PD + 262144;
  const size_t OFF_HF   = OFF_XF + 131072;
  const size_t OFF_HF2  = OFF_HF + 131072;
  const size_t OFF_PF   = OFF_HF2 + 131072;
  const size_t TOTAL    = OFF_PF + 262144;

  float* ss   = ws + OFF_SS;
  float* lacc = ws + OFF_LACC;
  float* tn   = ws + OFF_TN;
  float* x0   = ws + OFF_X0;
  float* x0r  = ws + OFF_X0R;
  float* x    = ws + OFF_X;
  float* h    = ws + OFF_H;
  float* q    = ws + OFF_QKVY;
  float* kk   = ws + OFF_QKVY + 2097152;
  float* vv   = ws + OFF_QKVY + 4194304;
  float* yb   = ws + OFF_QKVY + 6291456;
  float* u    = ws + OFF_QKVY;  // alias (MLP phase only)
  float* xo   = ws + OFF_XO;
  float* hd   = ws + OFF_HD;
  float* hd2  = ws + OFF_HD2;
  float* pd   = ws + OFF_PD;
  float* xf   = ws + OFF_XF;
  float* hf   = ws + OFF_HF;
  float* hf2  = ws + OFF_HF2;
  float* pf   = ws + OFF_PF;
  float* out_f = (float*)d_out;   // OUTPUT IS FLOAT32

  static const int EXPECTED[39] = {
      262144, 4096, 4096, 64, 64, 32768, 512, 3072, 3072, 3072, 3072,
      1572864, 3072, 1572864, 3072, 1572864, 3072, 1572864, 3072,
      6291456, 12288, 6291456, 3072, 512, 512, 131072, 256, 65536, 256,
      256, 256, 16384, 64, 65536, 256, 256, 256, 131072, 512};
  bool manifest_ok = (n_in == 39) && (ws_size >= TOTAL * sizeof(float));
  if (manifest_ok)
    for (int i = 0; i < 39; ++i)
      if (in_sizes[i] != EXPECTED[i]) { manifest_ok = false; break; }
  if (!manifest_ok) {
    hipLaunchKernelGGL(sentinel_kernel, dim3((out_size + 255) / 256), dim3(256), 0, stream,
                       out_f, out_size, 2000.0f);
    return;
  }

  const float* tok    = (const float*)d_in[0];
  const float* mask   = (const float*)d_in[2];
  const float* bn_g   = (const float*)d_in[3];
  const float* bn_b   = (const float*)d_in[4];
  const float* We     = (const float*)d_in[5];
  const float* be     = (const float*)d_in[6];
  const float* ln1_g  = (const float*)d_in[7];
  const float* ln1_b  = (const float*)d_in[8];
  const float* ln2_g  = (const float*)d_in[9];
  const float* ln2_b  = (const float*)d_in[10];
  const float* Wq     = (const float*)d_in[11];
  const float* bq     = (const float*)d_in[12];
  const float* Wk     = (const float*)d_in[13];
  const float* bk     = (const float*)d_in[14];
  const float* Wv     = (const float*)d_in[15];
  const float* bv     = (const float*)d_in[16];
  const float* Wo     = (const float*)d_in[17];
  const float* bo     = (const float*)d_in[18];
  const float* W1     = (const float*)d_in[19];
  const float* b1     = (const float*)d_in[20];
  const float* W2     = (const float*)d_in[21];
  const float* b2     = (const float*)d_in[22];
  const float* lnf_g  = (const float*)d_in[23];
  const float* lnf_b  = (const float*)d_in[24];
  const float* Wp     = (const float*)d_in[25];
  const float* bp     = (const float*)d_in[26];
  const float* Wd1    = (const float*)d_in[27];
  const float* bd1    = (const float*)d_in[28];
  const float* lnd_g  = (const float*)d_in[29];
  const float* lnd_b  = (const float*)d_in[30];
  const float* Wd2    = (const float*)d_in[31];
  const float* bd2    = (const float*)d_in[32];
  const float* Wf1    = (const float*)d_in[33];
  const float* bf1    = (const float*)d_in[34];
  const float* lnfr_g = (const float*)d_in[35];
  const float* lnfr_b = (const float*)d_in[36];
  const float* Wf2    = (const float*)d_in[37];
  const float* bf2    = (const float*)d_in[38];

  auto G = [&](int act, const float* A, const float* W, const float* bias,
               const float* resid, float* out, int M, int N, int K) {
    dim3 g(N / 64, M / 64), b(256);
    if (act == 0) hipLaunchKernelGGL((gemm3<0>), g, b, 0, stream, A, W, bias, resid, out, M, N, K);
    else if (act == 1) hipLaunchKernelGGL((gemm3<1>), g, b, 0, stream, A, W, bias, resid, out, M, N, K);
    else hipLaunchKernelGGL((gemm3<2>), g, b, 0, stream, A, W, bias, resid, out, M, N, K);
  };

  hipMemsetAsync(lacc, 0, 4 * sizeof(float), stream);
  hipLaunchKernelGGL(bn_stats_kernel, dim3(64), dim3(256), 0, stream, tok, bn_g, bn_b, ss);
  hipLaunchKernelGGL(tn_kernel, dim3(1024), dim3(256), 0, stream, tok, ss, tn);
  G(0, tn, We, be, nullptr, x0, 4096, 512, 64);
  hipLaunchKernelGGL(reverse_kernel, dim3(8192), dim3(256), 0, stream, x0, x0r);

  for (int dir = 0; dir < 2; ++dir) {
    const float* xin = dir ? x0r : x0;
    for (int l = 0; l < 6; ++l) {
      const float* xl = (l == 0) ? xin : x;
      hipLaunchKernelGGL(ln_kernel, dim3(4096), dim3(256), 0, stream,
                         xl, ln1_g + l * 512, ln1_b + l * 512, h, 512);
      // fused QKV (N=3*512), MFMA bf16x3
      hipLaunchKernelGGL((gemm_mfma<0, 0, 1>), dim3(12, 32, 1), dim3(256), 0, stream,
                         h, Wq + (size_t)l * 262144, Wk + (size_t)l * 262144, Wv + (size_t)l * 262144,
                         bq + l * 512, bk + l * 512, bv + l * 512, nullptr,
                         q, kk, vv, 4096, 512, 512, 512);
      hipLaunchKernelGGL(attn_flash, dim3(512), dim3(256), 0, stream,
                         q, kk, vv, mask, yb, dir);
      // O-proj with fused residual
      hipLaunchKernelGGL((gemm_mfma<0, 0, 0>), dim3(4, 32, 1), dim3(256), 0, stream,
                         yb, Wo + (size_t)l * 262144, nullptr, nullptr,
                         bo + l * 512, nullptr, nullptr, xl,
                         x, nullptr, nullptr, 4096, 512, 512, 512);
      hipLaunchKernelGGL(ln_kernel, dim3(4096), dim3(256), 0, stream,
                         x, ln2_g + l * 512, ln2_b + l * 512, h, 512);
      // MLP up + gelu
      hipLaunchKernelGGL((gemm_mfma<1, 0, 0>), dim3(16, 32, 1), dim3(256), 0, stream,
                         h, W1 + (size_t)l * 1048576, nullptr, nullptr,
                         b1 + l * 2048, nullptr, nullptr, nullptr,
                         u, nullptr, nullptr, 4096, 2048, 512, 512);
      // MLP down: split-K=2, atomicAdd into x (x already holds residual)
      hipLaunchKernelGGL((gemm_mfma<0, 1, 0>), dim3(4, 32, 2), dim3(256), 0, stream,
                         u, W2 + (size_t)l * 1048576, nullptr, nullptr,
                         b2 + l * 512, nullptr, nullptr, nullptr,
                         x, nullptr, nullptr, 4096, 512, 2048, 1024);
    }
    hipLaunchKernelGGL(ln_kernel, dim3(4096), dim3(256), 0, stream, x, lnf_g, lnf_b, h, 512);
    G(0, h, Wp, bp, nullptr, xo, 4096, 256, 512);
    G(2, xo, Wd1, bd1, nullptr, hd, 4096, 256, 256);
    hipLaunchKernelGGL(ln_kernel, dim3(4096), dim3(256), 0, stream, hd, lnd_g, lnd_b, hd2, 256);
    G(0, hd2, Wd2, bd2, nullptr, pd, 4096, 64, 256);
    hipLaunchKernelGGL(loss_reg_kernel, dim3(256), dim3(256), 0, stream,
                       pd, tok, mask, lacc + (dir ? 1 : 0), dir);
    hipLaunchKernelGGL(frame_mean_kernel, dim3(512), dim3(256), 0, stream,
                       xo, xf, dir == 0 ? out_f : (float*)nullptr);
    G(2, xf, Wf1, bf1, nullptr, hf, 512, 256, 256);
    hipLaunchKernelGGL(ln_kernel, dim3(512), dim3(256), 0, stream, hf, lnfr_g, lnfr_b, hf2, 256);
    G(0, hf2, Wf2, bf2, nullptr, pf, 512, 512, 256);
    hipLaunchKernelGGL(loss_fr_kernel, dim3(256), dim3(256), 0, stream,
                       pf, tok, mask, lacc + (dir ? 3 : 2), dir);
  }
  hipLaunchKernelGGL(finalize_kernel, dim3(1), dim3(64), 0, stream, lacc, out_f);
}

// Round 3
// 3539.734 us; speedup vs baseline: 3.6258x; 1.1902x over previous
//
#include <hip/hip_runtime.h>
#include <math.h>

typedef short short8 __attribute__((ext_vector_type(8)));
typedef float f32x4 __attribute__((ext_vector_type(4)));

// ---------------- helpers ----------------
__device__ __forceinline__ float block_reduce(float v, float* red) {
  int tid = threadIdx.x;
  red[tid] = v; __syncthreads();
  for (int s = 128; s >= 1; s >>= 1) {
    if (tid < s) red[tid] += red[tid + s];
    __syncthreads();
  }
  float r = red[0];
  __syncthreads();
  return r;
}

// f32 -> (hi bf16, lo bf16) split, packed pairwise into uints (elem k in low 16).
__device__ __forceinline__ void cvt2(float a, float b, unsigned& hp, unsigned& lp) {
  unsigned ua = __float_as_uint(a), ub = __float_as_uint(b);
  unsigned ha = (ua + 0x8000u) & 0xffff0000u;
  unsigned hb = (ub + 0x8000u) & 0xffff0000u;
  float la = a - __uint_as_float(ha);
  float lb = b - __uint_as_float(hb);
  hp = (ha >> 16) | hb;
  lp = (__float_as_uint(la) >> 16) | (__float_as_uint(lb) & 0xffff0000u);
}

union U8 { unsigned u[4]; short8 s; };

__global__ __launch_bounds__(256) void sentinel_kernel(float* __restrict__ out, int n, float v) {
  int i = blockIdx.x * 256 + threadIdx.x;
  if (i < n) out[i] = v;
}

// ---------------- BatchNorm stats ----------------
__global__ __launch_bounds__(256) void bn_stats_kernel(
    const float* __restrict__ tok, const float* __restrict__ g,
    const float* __restrict__ bb, float* __restrict__ ss) {
  __shared__ float red[256];
  const int d = blockIdx.x;
  float sum = 0.f, sumsq = 0.f;
  for (int s = threadIdx.x; s < 4096; s += 256) {
    float v = tok[s * 64 + d];
    sum += v; sumsq += v * v;
  }
  sum = block_reduce(sum, red);
  sumsq = block_reduce(sumsq, red);
  if (threadIdx.x == 0) {
    float mu = sum * (1.f / 4096.f);
    float var = sumsq * (1.f / 4096.f) - mu * mu;
    float sc = g[d] * rsqrtf(fmaxf(var, 0.f) + 1e-5f);
    ss[d] = sc;
    ss[64 + d] = bb[d] - mu * sc;
  }
}

__global__ __launch_bounds__(256) void tn_kernel(
    const float* __restrict__ tok, const float* __restrict__ ss,
    float* __restrict__ tn) {
  int idx = blockIdx.x * 256 + threadIdx.x;
  int d = idx & 63;
  tn[idx] = tok[idx] * ss[d] + ss[64 + d];
}

__global__ __launch_bounds__(256) void reverse_kernel(
    const float* __restrict__ x0, float* __restrict__ x0r) {
  int idx = blockIdx.x * 256 + threadIdx.x;
  int row = idx >> 9, e = idx & 511;
  int b = row >> 10, t = row & 1023;
  x0r[idx] = x0[((size_t)((b << 10) + (1023 - t))) * 512 + e];
}

// ---------------- row LayerNorm (N = 512 or 256) ----------------
__global__ __launch_bounds__(256) void ln_kernel(
    const float* __restrict__ x, const float* __restrict__ g,
    const float* __restrict__ b, float* __restrict__ out, int N) {
  __shared__ float red[256];
  const size_t r = blockIdx.x;
  const int tid = threadIdx.x;
  float v0 = x[r * N + tid];
  float v1 = (N > 256) ? x[r * N + 256 + tid] : 0.f;
  float sum = block_reduce(v0 + v1, red);
  float sumsq = block_reduce(v0 * v0 + v1 * v1, red);
  float mean = sum / (float)N;
  float var = sumsq / (float)N - mean * mean;
  float rs = rsqrtf(fmaxf(var, 0.f) + 1e-5f);
  out[r * N + tid] = (v0 - mean) * rs * g[tid] + b[tid];
  if (N > 256)
    out[r * N + 256 + tid] = (v1 - mean) * rs * g[256 + tid] + b[256 + tid];
}

// --------- small GEMM (f32): out[M,N] = A@W + bias (+resid)(act) ---------
#define BK 16
template <int ACT>  // 0 none, 1 gelu(exact), 2 tanh
__global__ __launch_bounds__(256) void gemm3(
    const float* __restrict__ A, const float* __restrict__ W,
    const float* __restrict__ bias, const float* resid,
    float* out, int M, int N, int K) {
  __shared__ float As[BK][64 + 4];
  __shared__ float Bs[BK][64 + 4];
  const int tid = threadIdx.x;
  const int tx = tid & 15, ty = tid >> 4;
  const int n0 = blockIdx.x * 64, m0 = blockIdx.y * 64;
  float acc[4][4] = {};
  for (int k0 = 0; k0 < K; k0 += BK) {
    {
      int m = tid >> 2, kq = tid & 3;
      float4 a4 = *reinterpret_cast<const float4*>(A + (size_t)(m0 + m) * K + k0 + kq * 4);
      As[kq * 4 + 0][m] = a4.x; As[kq * 4 + 1][m] = a4.y;
      As[kq * 4 + 2][m] = a4.z; As[kq * 4 + 3][m] = a4.w;
    }
    {
      int kk = tid >> 4, nq = tid & 15;
      float4 b4 = *reinterpret_cast<const float4*>(W + (size_t)(k0 + kk) * N + n0 + nq * 4);
      Bs[kk][nq * 4 + 0] = b4.x; Bs[kk][nq * 4 + 1] = b4.y;
      Bs[kk][nq * 4 + 2] = b4.z; Bs[kk][nq * 4 + 3] = b4.w;
    }
    __syncthreads();
#pragma unroll
    for (int kq = 0; kq < BK; ++kq) {
      float4 av = *reinterpret_cast<const float4*>(&As[kq][ty * 4]);
      float4 bv = *reinterpret_cast<const float4*>(&Bs[kq][tx * 4]);
      acc[0][0] += av.x * bv.x; acc[0][1] += av.x * bv.y; acc[0][2] += av.x * bv.z; acc[0][3] += av.x * bv.w;
      acc[1][0] += av.y * bv.x; acc[1][1] += av.y * bv.y; acc[1][2] += av.y * bv.z; acc[1][3] += av.y * bv.w;
      acc[2][0] += av.z * bv.x; acc[2][1] += av.z * bv.y; acc[2][2] += av.z * bv.z; acc[2][3] += av.z * bv.w;
      acc[3][0] += av.w * bv.x; acc[3][1] += av.w * bv.y; acc[3][2] += av.w * bv.z; acc[3][3] += av.w * bv.w;
    }
    __syncthreads();
  }
#pragma unroll
  for (int i = 0; i < 4; ++i) {
    int m = m0 + ty * 4 + i;
#pragma unroll
    for (int j = 0; j < 4; ++j) {
      int n = n0 + tx * 4 + j;
      float v = acc[i][j] + bias[n];
      if (resid) v += resid[(size_t)m * N + n];
      if (ACT == 1) v = 0.5f * v * (1.f + erff(v * 0.70710678118654752f));
      if (ACT == 2) v = tanhf(v);
      out[(size_t)m * N + n] = v;
    }
  }
}

// --------- MFMA GEMM, fp32 via bf16x3 split. 128x128x32 tiles, 4 waves. ---------
template <int ACT, int ATOMIC, int FUSE3>  // ACT: 0 none, 1 gelu, 2 tanh
__global__ __launch_bounds__(256, 2) void gemm_mfma(
    const float* __restrict__ A,
    const float* __restrict__ B0, const float* __restrict__ B1, const float* __restrict__ B2,
    const float* __restrict__ bias0, const float* __restrict__ bias1, const float* __restrict__ bias2,
    const float* __restrict__ resid,
    float* __restrict__ C0, float* __restrict__ C1, float* __restrict__ C2,
    int M, int Nsec, int K, int KZ) {
  __shared__ unsigned Ah[128][20];
  __shared__ unsigned Al[128][20];
  __shared__ unsigned Bh[128][20];
  __shared__ unsigned Bl[128][20];
  const int tid = threadIdx.x;
  const int lane = tid & 63, wid = tid >> 6;
  const int wr = wid >> 1, wc = wid & 1;
  const int lr = lane & 15, lq = lane >> 4;

  int nb = blockIdx.x, sec = 0;
  if (FUSE3) { sec = nb >> 2; nb &= 3; }
  const float* Bg = FUSE3 ? (sec == 0 ? B0 : (sec == 1 ? B1 : B2)) : B0;
  const float* bias = FUSE3 ? (sec == 0 ? bias0 : (sec == 1 ? bias1 : bias2)) : bias0;
  float* C = FUSE3 ? (sec == 0 ? C0 : (sec == 1 ? C1 : C2)) : C0;
  const int n0 = nb * 128;
  const int m0 = blockIdx.y * 128;
  const int kbase = blockIdx.z * KZ;

  f32x4 acc[4][4];
#pragma unroll
  for (int i = 0; i < 4; ++i)
#pragma unroll
    for (int j = 0; j < 4; ++j) { acc[i][j][0] = 0.f; acc[i][j][1] = 0.f; acc[i][j][2] = 0.f; acc[i][j][3] = 0.f; }

  const int nB = tid & 127;
  const int khalf = tid >> 7;

  for (int k0 = kbase; k0 < kbase + KZ; k0 += 32) {
#pragma unroll
    for (int i = 0; i < 4; ++i) {
      int idx = i * 256 + tid;
      int row = idx >> 3, c4 = idx & 7;
      float4 a4 = *reinterpret_cast<const float4*>(A + (size_t)(m0 + row) * K + k0 + c4 * 4);
      unsigned h0, l0, h1, l1;
      cvt2(a4.x, a4.y, h0, l0);
      cvt2(a4.z, a4.w, h1, l1);
      *reinterpret_cast<uint2*>(&Ah[row][c4 * 2]) = make_uint2(h0, h1);
      *reinterpret_cast<uint2*>(&Al[row][c4 * 2]) = make_uint2(l0, l1);
    }
    {
      const float* bp = Bg + (size_t)(k0 + khalf * 16) * Nsec + n0 + nB;
      float w[16];
#pragma unroll
      for (int r = 0; r < 16; ++r) w[r] = bp[(size_t)r * Nsec];
      unsigned hp[8], lp[8];
#pragma unroll
      for (int j = 0; j < 8; ++j) cvt2(w[2 * j], w[2 * j + 1], hp[j], lp[j]);
      int sw = nB & 3;
      int s0 = (khalf * 2) ^ sw, s1 = (khalf * 2 + 1) ^ sw;
      *reinterpret_cast<uint4*>(&Bh[nB][s0 * 4]) = make_uint4(hp[0], hp[1], hp[2], hp[3]);
      *reinterpret_cast<uint4*>(&Bh[nB][s1 * 4]) = make_uint4(hp[4], hp[5], hp[6], hp[7]);
      *reinterpret_cast<uint4*>(&Bl[nB][s0 * 4]) = make_uint4(lp[0], lp[1], lp[2], lp[3]);
      *reinterpret_cast<uint4*>(&Bl[nB][s1 * 4]) = make_uint4(lp[4], lp[5], lp[6], lp[7]);
    }
    __syncthreads();
    short8 ah[4], al[4], bh[4], bl[4];
#pragma unroll
    for (int mi = 0; mi < 4; ++mi) {
      int row = wr * 64 + mi * 16 + lr;
      ah[mi] = *reinterpret_cast<const short8*>(&Ah[row][lq * 4]);
      al[mi] = *reinterpret_cast<const short8*>(&Al[row][lq * 4]);
    }
#pragma unroll
    for (int ni = 0; ni < 4; ++ni) {
      int n = wc * 64 + ni * 16 + lr;
      int sp = lq ^ (n & 3);
      bh[ni] = *reinterpret_cast<const short8*>(&Bh[n][sp * 4]);
      bl[ni] = *reinterpret_cast<const short8*>(&Bl[n][sp * 4]);
    }
#pragma unroll
    for (int mi = 0; mi < 4; ++mi)
#pragma unroll
      for (int ni = 0; ni < 4; ++ni) {
        acc[mi][ni] = __builtin_amdgcn_mfma_f32_16x16x32_bf16(ah[mi], bh[ni], acc[mi][ni], 0, 0, 0);
        acc[mi][ni] = __builtin_amdgcn_mfma_f32_16x16x32_bf16(ah[mi], bl[ni], acc[mi][ni], 0, 0, 0);
        acc[mi][ni] = __builtin_amdgcn_mfma_f32_16x16x32_bf16(al[mi], bh[ni], acc[mi][ni], 0, 0, 0);
      }
    __syncthreads();
  }

#pragma unroll
  for (int mi = 0; mi < 4; ++mi) {
#pragma unroll
    for (int r = 0; r < 4; ++r) {
      int grow = m0 + wr * 64 + mi * 16 + lq * 4 + r;
#pragma unroll
      for (int ni = 0; ni < 4; ++ni) {
        int col = wc * 64 + ni * 16 + lr;
        float v = acc[mi][ni][r];
        if (ATOMIC) {
          if (blockIdx.z == 0) v += bias[n0 + col];
          atomicAdd(&C[(size_t)grow * Nsec + n0 + col], v);
        } else {
          v += bias[n0 + col];
          if (resid) v += resid[(size_t)grow * Nsec + n0 + col];
          if (ACT == 1) v = 0.5f * v * (1.f + erff(v * 0.70710678118654752f));
          if (ACT == 2) v = tanhf(v);
          C[(size_t)grow * Nsec + n0 + col] = v;
        }
      }
    }
  }
}

// ---------------- attention: MFMA flash, bf16x3, 64x64 tiles ----------------
// One block per (b, h, qt). 4 waves x 16 query rows. S = Q K^T via 16x16x32
// bf16 MFMA (hi*hi + hi*lo + lo*hi); online softmax in C-fragment registers
// (row = lq*4+reg, key = kf*16+lr, shfl-reduce over 16 lanes); P re-shaped to
// A-fragments via a 68-padded f32 LDS round trip; PV again x3 MFMA with V
// staged transposed (bf16 hi/lo). All LDS tiles use a slot^(row&7) XOR swizzle
// so b128 fragment reads are <=2-way bank aliases (free). Q A-frags preloaded
// to registers; Q staging LDS is reused for V^T. 49.3 KB LDS, 3 syncs/step.
__global__ __launch_bounds__(256, 2) void attn_mfma(
    const float* __restrict__ q, const float* __restrict__ k,
    const float* __restrict__ v, const float* __restrict__ mask,
    float* __restrict__ y, int rev) {
  __shared__ unsigned SH[4096];       // 16KB: Q staging, then V^T hi/lo
  __shared__ unsigned KhL[2048];      // 8KB  K hi
  __shared__ unsigned KlL[2048];      // 8KB  K lo
  __shared__ float PU[64 * 68];       // 17KB P (f32)
  __shared__ float km[64];
  unsigned* VhL = SH;
  unsigned* VlL = SH + 2048;

  const int tid = threadIdx.x;
  const int lane = tid & 63, w = tid >> 6;
  const int lr = lane & 15, lq = lane >> 4;

  const int id = blockIdx.x;          // complementary-pair mapping
  const int top = id >> 8;
  const int r5 = id & 255;
  const int qt = top ? (15 - (r5 >> 4)) : (r5 >> 4);
  const int bh_ = (r5 & 15) | (top << 4);
  const int b = bh_ >> 3, h = bh_ & 7;

  const size_t base = (size_t)(b * 1024) * 512 + h * 64;

  // ---- stage Q (scaled 1/8) into SH, swizzled ----
  {
    const float* qp = q + base + (size_t)(qt * 64) * 512;
    int row = tid >> 2, f4 = tid & 3;
#pragma unroll
    for (int j = 0; j < 4; ++j) {
      int dk = f4 * 4 + j * 16;
      float4 a = *reinterpret_cast<const float4*>(qp + (size_t)row * 512 + dk);
      unsigned h0, l0, h1, l1;
      cvt2(a.x * 0.125f, a.y * 0.125f, h0, l0);
      cvt2(a.z * 0.125f, a.w * 0.125f, h1, l1);
      int phys = (dk >> 3) ^ (row & 7);
      int off = row * 32 + phys * 4 + (f4 & 1) * 2;
      *reinterpret_cast<uint2*>(&SH[off]) = make_uint2(h0, h1);
      *reinterpret_cast<uint2*>(&KhL[off]) = make_uint2(l0, l1);  // temp: Q-lo in KhL
    }
  }
  __syncthreads();
  // preload Q A-fragments (row = w*16+lr)
  short8 qa_h[2], qa_l[2];
#pragma unroll
  for (int ks = 0; ks < 2; ++ks) {
    int row = w * 16 + lr;
    int phys = (lq + ks * 4) ^ (row & 7);
    qa_h[ks] = *reinterpret_cast<const short8*>(&SH[row * 32 + phys * 4]);
    qa_l[ks] = *reinterpret_cast<const short8*>(&KhL[row * 32 + phys * 4]);
  }
  __syncthreads();  // SH/KhL now free for V^T / K tiles

  float m_[4], l_[4] = {0.f, 0.f, 0.f, 0.f};
  f32x4 o_[4];
#pragma unroll
  for (int r = 0; r < 4; ++r) m_[r] = -1e30f;
#pragma unroll
  for (int df = 0; df < 4; ++df) { o_[df][0] = 0.f; o_[df][1] = 0.f; o_[df][2] = 0.f; o_[df][3] = 0.f; }

  for (int kt = 0; kt <= qt; ++kt) {
    const float* kp = k + base + (size_t)(kt * 64) * 512;
    const float* vp = v + base + (size_t)(kt * 64) * 512;
    // ---- stage K (row-major, swizzled) ----
    {
      int row = tid >> 2, f4 = tid & 3;
#pragma unroll
      for (int j = 0; j < 4; ++j) {
        int dk = f4 * 4 + j * 16;
        float4 a = *reinterpret_cast<const float4*>(kp + (size_t)row * 512 + dk);
        unsigned h0, l0, h1, l1;
        cvt2(a.x, a.y, h0, l0);
        cvt2(a.z, a.w, h1, l1);
        int phys = (dk >> 3) ^ (row & 7);
        int off = row * 32 + phys * 4 + (f4 & 1) * 2;
        *reinterpret_cast<uint2*>(&KhL[off]) = make_uint2(h0, h1);
        *reinterpret_cast<uint2*>(&KlL[off]) = make_uint2(l0, l1);
      }
    }
    // ---- stage V^T (key-pairs packed per uint, swizzled) ----
    {
      int d = tid & 63, g = tid >> 6;
#pragma unroll
      for (int j = 0; j < 8; ++j) {
        int kpair = (g + j * 4 + (d >> 3)) & 31;
        float v0 = vp[(size_t)(kpair * 2) * 512 + d];
        float v1 = vp[(size_t)(kpair * 2 + 1) * 512 + d];
        unsigned hh, ll;
        cvt2(v0, v1, hh, ll);
        int phys = (kpair >> 2) ^ (d & 7);
        int off = d * 32 + phys * 4 + (kpair & 3);
        VhL[off] = hh; VlL[off] = ll;
      }
    }
    if (tid < 64) {
      int s = kt * 64 + tid;
      km[tid] = mask[b * 1024 + (rev ? (1023 - s) : s)];
    }
    __syncthreads();

    // ---- S = Q K^T (x3 MFMA) ----
    f32x4 sacc[4];
#pragma unroll
    for (int kf = 0; kf < 4; ++kf) { sacc[kf][0] = 0.f; sacc[kf][1] = 0.f; sacc[kf][2] = 0.f; sacc[kf][3] = 0.f; }
#pragma unroll
    for (int ks = 0; ks < 2; ++ks) {
#pragma unroll
      for (int kf = 0; kf < 4; ++kf) {
        int col = kf * 16 + lr;
        int phys = (lq + ks * 4) ^ (lr & 7);
        short8 kbh = *reinterpret_cast<const short8*>(&KhL[col * 32 + phys * 4]);
        short8 kbl = *reinterpret_cast<const short8*>(&KlL[col * 32 + phys * 4]);
        sacc[kf] = __builtin_amdgcn_mfma_f32_16x16x32_bf16(qa_h[ks], kbh, sacc[kf], 0, 0, 0);
        sacc[kf] = __builtin_amdgcn_mfma_f32_16x16x32_bf16(qa_h[ks], kbl, sacc[kf], 0, 0, 0);
        sacc[kf] = __builtin_amdgcn_mfma_f32_16x16x32_bf16(qa_l[ks], kbh, sacc[kf], 0, 0, 0);
      }
    }

    // ---- online softmax in registers ----
    const bool diag = (kt == qt);
    float kmv[4];
#pragma unroll
    for (int kf = 0; kf < 4; ++kf) kmv[kf] = km[kf * 16 + lr];
#pragma unroll
    for (int r = 0; r < 4; ++r) {
      int fi = (w * 16 + lq * 4 + r) >> 3;
      float mt = -1e30f;
#pragma unroll
      for (int kf = 0; kf < 4; ++kf) {
        int key = kf * 16 + lr;
        bool ok = (kmv[kf] > 0.f) && (!diag || ((key >> 3) <= fi));
        float x = ok ? sacc[kf][r] : -1e30f;
        sacc[kf][r] = x;
        mt = fmaxf(mt, x);
      }
      mt = fmaxf(mt, __shfl_xor(mt, 1, 16));
      mt = fmaxf(mt, __shfl_xor(mt, 2, 16));
      mt = fmaxf(mt, __shfl_xor(mt, 4, 16));
      mt = fmaxf(mt, __shfl_xor(mt, 8, 16));
      float mn = fmaxf(m_[r], mt);
      float al = __expf(m_[r] - mn);
      m_[r] = mn;
      float rs = 0.f;
#pragma unroll
      for (int kf = 0; kf < 4; ++kf) {
        float sv = sacc[kf][r];
        float p = (sv > -1e29f) ? __expf(sv - mn) : 0.f;
        sacc[kf][r] = p;
        rs += p;
      }
      rs += __shfl_xor(rs, 1, 16);
      rs += __shfl_xor(rs, 2, 16);
      rs += __shfl_xor(rs, 4, 16);
      rs += __shfl_xor(rs, 8, 16);
      l_[r] = l_[r] * al + rs;
#pragma unroll
      for (int df = 0; df < 4; ++df) o_[df][r] *= al;
    }
    // ---- write P (f32, 68-stride) ----
#pragma unroll
    for (int kf = 0; kf < 4; ++kf)
#pragma unroll
      for (int r = 0; r < 4; ++r)
        PU[(w * 16 + lq * 4 + r) * 68 + kf * 16 + lr] = sacc[kf][r];
    __syncthreads();

    // ---- O += P V (x3 MFMA) ----
#pragma unroll
    for (int ks = 0; ks < 2; ++ks) {
      const float* pp = &PU[(w * 16 + lr) * 68 + ks * 32 + lq * 8];
      float4 p0 = *reinterpret_cast<const float4*>(pp);
      float4 p1 = *reinterpret_cast<const float4*>(pp + 4);
      U8 th, tl;
      cvt2(p0.x, p0.y, th.u[0], tl.u[0]);
      cvt2(p0.z, p0.w, th.u[1], tl.u[1]);
      cvt2(p1.x, p1.y, th.u[2], tl.u[2]);
      cvt2(p1.z, p1.w, th.u[3], tl.u[3]);
      short8 pa_h = th.s, pa_l = tl.s;
#pragma unroll
      for (int df = 0; df < 4; ++df) {
        int col = df * 16 + lr;
        int phys = (lq + ks * 4) ^ (lr & 7);
        short8 vbh = *reinterpret_cast<const short8*>(&VhL[col * 32 + phys * 4]);
        short8 vbl = *reinterpret_cast<const short8*>(&VlL[col * 32 + phys * 4]);
        o_[df] = __builtin_amdgcn_mfma_f32_16x16x32_bf16(pa_h, vbh, o_[df], 0, 0, 0);
        o_[df] = __builtin_amdgcn_mfma_f32_16x16x32_bf16(pa_h, vbl, o_[df], 0, 0, 0);
        o_[df] = __builtin_amdgcn_mfma_f32_16x16x32_bf16(pa_l, vbh, o_[df], 0, 0, 0);
      }
    }
    __syncthreads();
  }

  // ---- normalize + write ----
#pragma unroll
  for (int r = 0; r < 4; ++r) {
    float inv = 1.f / fmaxf(l_[r], 1e-30f);
    int qrow = qt * 64 + w * 16 + lq * 4 + r;
#pragma unroll
    for (int df = 0; df < 4; ++df)
      y[base + (size_t)qrow * 512 + df * 16 + lr] = o_[df][r] * inv;
  }
}

// ---------------- frame mean (+ FLOAT32 output write) ----------------
__global__ __launch_bounds__(256) void frame_mean_kernel(
    const float* __restrict__ xo, float* __restrict__ xf,
    float* __restrict__ outf) {
  int row = blockIdx.x;       // b*128+tf
  int o = threadIdx.x;
  float s = 0.f;
#pragma unroll
  for (int c = 0; c < 8; ++c) s += xo[((size_t)row * 8 + c) * 256 + o];
  s *= 0.125f;
  xf[row * 256 + o] = s;
  if (outf) outf[row * 256 + o] = s;
}

// ---------------- losses ----------------
__global__ __launch_bounds__(256) void loss_reg_kernel(
    const float* __restrict__ pd, const float* __restrict__ tok,
    const float* __restrict__ mask, float* __restrict__ acc, int rev) {
  __shared__ float red[256];
  float local = 0.f;
  for (int idx = blockIdx.x * 256 + threadIdx.x; idx < 260096; idx += gridDim.x * 256) {
    int b = idx / 65024, r2 = idx % 65024;
    int t = r2 >> 6, d = r2 & 63;
    float pred = pd[((size_t)((b << 10) + t)) * 64 + d] * mask[(b << 10) + t];
    int tt = rev ? (1015 - t) : (t + 8);
    float tgt = tok[((size_t)((b << 10) + tt)) * 64 + d] * mask[(b << 10) + tt];
    float df = pred - tgt;
    local += df * df;
  }
  float s = block_reduce(local, red);
  if (threadIdx.x == 0) atomicAdd(acc, s);
}

__global__ __launch_bounds__(256) void loss_fr_kernel(
    const float* __restrict__ pf, const float* __restrict__ tok,
    const float* __restrict__ mask, float* __restrict__ acc, int rev) {
  __shared__ float red[256];
  float local = 0.f;
  for (int idx = blockIdx.x * 256 + threadIdx.x; idx < 260096; idx += gridDim.x * 256) {
    int b = idx / 65024, r2 = idx % 65024;
    int i = r2 >> 9, u = r2 & 511;
    float pred = pf[((size_t)(b * 128 + i)) * 512 + u];
    int c = u >> 6;
    int t = rev ? ((126 - i) * 8 + c) : ((i + 1) * 8 + c);
    float tgt = tok[((size_t)((b << 10) + t)) * 64 + (u & 63)] * mask[(b << 10) + t];
    float df = pred - tgt;
    local += df * df;
  }
  float s = block_reduce(local, red);
  if (threadIdx.x == 0) atomicAdd(acc, s);
}

__global__ void finalize_kernel(const float* __restrict__ acc, float* __restrict__ out) {
  int i = threadIdx.x;
  if (i < 4) out[131072 + i] = acc[i] * (1.0f / 260096.0f);
}

extern "C" void kernel_launch(void* const* d_in, const int* in_sizes, int n_in,
                              void* d_out, int out_size, void* d_ws, size_t ws_size,
                              hipStream_t stream) {
  float* ws = (float*)d_ws;
  const size_t OFF_SS   = 0;
  const size_t OFF_LACC = 128;
  const size_t OFF_TN   = 256;
  const size_t OFF_X0   = OFF_TN + 262144;
  const size_t OFF_X0R  = OFF_X0 + 2097152;
  const size_t OFF_X    = OFF_X0R + 2097152;
  const size_t OFF_H    = OFF_X + 2097152;
  const size_t OFF_QKVY = OFF_H + 2097152;
  const size_t OFF_XO   = OFF_QKVY + 8388608;
  const size_t OFF_HD   = OFF_XO + 1048576;
  const size_t OFF_HD2  = OFF_HD + 1048576;
  const size_t OFF_PD   = OFF_HD2 + 1048576;
  const size_t OFF_XF   = OFF_PD + 262144;
  const size_t OFF_HF   = OFF_XF + 131072;
  const size_t OFF_HF2  = OFF_HF + 131072;
  const size_t OFF_PF   = OFF_HF2 + 131072;
  const size_t TOTAL    = OFF_PF + 262144;

  float* ss   = ws + OFF_SS;
  float* lacc = ws + OFF_LACC;
  float* tn   = ws + OFF_TN;
  float* x0   = ws + OFF_X0;
  float* x0r  = ws + OFF_X0R;
  float* x    = ws + OFF_X;
  float* h    = ws + OFF_H;
  float* q    = ws + OFF_QKVY;
  float* kk   = ws + OFF_QKVY + 2097152;
  float* vv   = ws + OFF_QKVY + 4194304;
  float* yb   = ws + OFF_QKVY + 6291456;
  float* u    = ws + OFF_QKVY;  // alias (MLP phase only)
  float* xo   = ws + OFF_XO;
  float* hd   = ws + OFF_HD;
  float* hd2  = ws + OFF_HD2;
  float* pd   = ws + OFF_PD;
  float* xf   = ws + OFF_XF;
  float* hf   = ws + OFF_HF;
  float* hf2  = ws + OFF_HF2;
  float* pf   = ws + OFF_PF;
  float* out_f = (float*)d_out;   // OUTPUT IS FLOAT32

  static const int EXPECTED[39] = {
      262144, 4096, 4096, 64, 64, 32768, 512, 3072, 3072, 3072, 3072,
      1572864, 3072, 1572864, 3072, 1572864, 3072, 1572864, 3072,
      6291456, 12288, 6291456, 3072, 512, 512, 131072, 256, 65536, 256,
      256, 256, 16384, 64, 65536, 256, 256, 256, 131072, 512};
  bool manifest_ok = (n_in == 39) && (ws_size >= TOTAL * sizeof(float));
  if (manifest_ok)
    for (int i = 0; i < 39; ++i)
      if (in_sizes[i] != EXPECTED[i]) { manifest_ok = false; break; }
  if (!manifest_ok) {
    hipLaunchKernelGGL(sentinel_kernel, dim3((out_size + 255) / 256), dim3(256), 0, stream,
                       out_f, out_size, 2000.0f);
    return;
  }

  const float* tok    = (const float*)d_in[0];
  const float* mask   = (const float*)d_in[2];
  const float* bn_g   = (const float*)d_in[3];
  const float* bn_b   = (const float*)d_in[4];
  const float* We     = (const float*)d_in[5];
  const float* be     = (const float*)d_in[6];
  const float* ln1_g  = (const float*)d_in[7];
  const float* ln1_b  = (const float*)d_in[8];
  const float* ln2_g  = (const float*)d_in[9];
  const float* ln2_b  = (const float*)d_in[10];
  const float* Wq     = (const float*)d_in[11];
  const float* bq     = (const float*)d_in[12];
  const float* Wk     = (const float*)d_in[13];
  const float* bk     = (const float*)d_in[14];
  const float* Wv     = (const float*)d_in[15];
  const float* bv     = (const float*)d_in[16];
  const float* Wo     = (const float*)d_in[17];
  const float* bo     = (const float*)d_in[18];
  const float* W1     = (const float*)d_in[19];
  const float* b1     = (const float*)d_in[20];
  const float* W2     = (const float*)d_in[21];
  const float* b2     = (const float*)d_in[22];
  const float* lnf_g  = (const float*)d_in[23];
  const float* lnf_b  = (const float*)d_in[24];
  const float* Wp     = (const float*)d_in[25];
  const float* bp     = (const float*)d_in[26];
  const float* Wd1    = (const float*)d_in[27];
  const float* bd1    = (const float*)d_in[28];
  const float* lnd_g  = (const float*)d_in[29];
  const float* lnd_b  = (const float*)d_in[30];
  const float* Wd2    = (const float*)d_in[31];
  const float* bd2    = (const float*)d_in[32];
  const float* Wf1    = (const float*)d_in[33];
  const float* bf1    = (const float*)d_in[34];
  const float* lnfr_g = (const float*)d_in[35];
  const float* lnfr_b = (const float*)d_in[36];
  const float* Wf2    = (const float*)d_in[37];
  const float* bf2    = (const float*)d_in[38];

  auto G = [&](int act, const float* A, const float* W, const float* bias,
               const float* resid, float* out, int M, int N, int K) {
    dim3 g(N / 64, M / 64), b(256);
    if (act == 0) hipLaunchKernelGGL((gemm3<0>), g, b, 0, stream, A, W, bias, resid, out, M, N, K);
    else if (act == 1) hipLaunchKernelGGL((gemm3<1>), g, b, 0, stream, A, W, bias, resid, out, M, N, K);
    else hipLaunchKernelGGL((gemm3<2>), g, b, 0, stream, A, W, bias, resid, out, M, N, K);
  };

  hipMemsetAsync(lacc, 0, 4 * sizeof(float), stream);
  hipLaunchKernelGGL(bn_stats_kernel, dim3(64), dim3(256), 0, stream, tok, bn_g, bn_b, ss);
  hipLaunchKernelGGL(tn_kernel, dim3(1024), dim3(256), 0, stream, tok, ss, tn);
  G(0, tn, We, be, nullptr, x0, 4096, 512, 64);
  hipLaunchKernelGGL(reverse_kernel, dim3(8192), dim3(256), 0, stream, x0, x0r);

  for (int dir = 0; dir < 2; ++dir) {
    const float* xin = dir ? x0r : x0;
    for (int l = 0; l < 6; ++l) {
      const float* xl = (l == 0) ? xin : x;
      hipLaunchKernelGGL(ln_kernel, dim3(4096), dim3(256), 0, stream,
                         xl, ln1_g + l * 512, ln1_b + l * 512, h, 512);
      // fused QKV (N=3*512), MFMA bf16x3
      hipLaunchKernelGGL((gemm_mfma<0, 0, 1>), dim3(12, 32, 1), dim3(256), 0, stream,
                         h, Wq + (size_t)l * 262144, Wk + (size_t)l * 262144, Wv + (size_t)l * 262144,
                         bq + l * 512, bk + l * 512, bv + l * 512, nullptr,
                         q, kk, vv, 4096, 512, 512, 512);
      hipLaunchKernelGGL(attn_mfma, dim3(512), dim3(256), 0, stream,
                         q, kk, vv, mask, yb, dir);
      // O-proj with fused residual
      hipLaunchKernelGGL((gemm_mfma<0, 0, 0>), dim3(4, 32, 1), dim3(256), 0, stream,
                         yb, Wo + (size_t)l * 262144, nullptr, nullptr,
                         bo + l * 512, nullptr, nullptr, xl,
                         x, nullptr, nullptr, 4096, 512, 512, 512);
      hipLaunchKernelGGL(ln_kernel, dim3(4096), dim3(256), 0, stream,
                         x, ln2_g + l * 512, ln2_b + l * 512, h, 512);
      // MLP up + gelu
      hipLaunchKernelGGL((gemm_mfma<1, 0, 0>), dim3(16, 32, 1), dim3(256), 0, stream,
                         h, W1 + (size_t)l * 1048576, nullptr, nullptr,
                         b1 + l * 2048, nullptr, nullptr, nullptr,
                         u, nullptr, nullptr, 4096, 2048, 512, 512);
      // MLP down: split-K=2, atomicAdd into x (x already holds residual)
      hipLaunchKernelGGL((gemm_mfma<0, 1, 0>), dim3(4, 32, 2), dim3(256), 0, stream,
                         u, W2 + (size_t)l * 1048576, nullptr, nullptr,
                         b2 + l * 512, nullptr, nullptr, nullptr,
                         x, nullptr, nullptr, 4096, 512, 2048, 1024);
    }
    hipLaunchKernelGGL(ln_kernel, dim3(4096), dim3(256), 0, stream, x, lnf_g, lnf_b, h, 512);
    // head projection + decoder first layer on MFMA (N=256)
    hipLaunchKernelGGL((gemm_mfma<0, 0, 0>), dim3(2, 32, 1), dim3(256), 0, stream,
                       h, Wp, nullptr, nullptr, bp, nullptr, nullptr, nullptr,
                       xo, nullptr, nullptr, 4096, 256, 512, 512);
    hipLaunchKernelGGL((gemm_mfma<2, 0, 0>), dim3(2, 32, 1), dim3(256), 0, stream,
                       xo, Wd1, nullptr, nullptr, bd1, nullptr, nullptr, nullptr,
                       hd, nullptr, nullptr, 4096, 256, 256, 256);
    hipLaunchKernelGGL(ln_kernel, dim3(4096), dim3(256), 0, stream, hd, lnd_g, lnd_b, hd2, 256);
    G(0, hd2, Wd2, bd2, nullptr, pd, 4096, 64, 256);
    hipLaunchKernelGGL(loss_reg_kernel, dim3(256), dim3(256), 0, stream,
                       pd, tok, mask, lacc + (dir ? 1 : 0), dir);
    hipLaunchKernelGGL(frame_mean_kernel, dim3(512), dim3(256), 0, stream,
                       xo, xf, dir == 0 ? out_f : (float*)nullptr);
    G(2, xf, Wf1, bf1, nullptr, hf, 512, 256, 256);
    hipLaunchKernelGGL(ln_kernel, dim3(512), dim3(256), 0, stream, hf, lnfr_g, lnfr_b, hf2, 256);
    G(0, hf2, Wf2, bf2, nullptr, pf, 512, 512, 256);
    hipLaunchKernelGGL(loss_fr_kernel, dim3(256), dim3(256), 0, stream,
                       pf, tok, mask, lacc + (dir ? 3 : 2), dir);
  }
  hipLaunchKernelGGL(finalize_kernel, dim3(1), dim3(64), 0, stream, lacc, out_f);
}

// Round 4
// 3473.618 us; speedup vs baseline: 3.6948x; 1.0190x over previous
//
#include <hip/hip_runtime.h>
#include <math.h>

typedef short short8 __attribute__((ext_vector_type(8)));
typedef float f32x4 __attribute__((ext_vector_type(4)));

// ---------------- helpers ----------------
__device__ __forceinline__ float block_reduce(float v, float* red) {
  int tid = threadIdx.x;
  red[tid] = v; __syncthreads();
  for (int s = 128; s >= 1; s >>= 1) {
    if (tid < s) red[tid] += red[tid + s];
    __syncthreads();
  }
  float r = red[0];
  __syncthreads();
  return r;
}

// f32 -> (hi bf16, lo bf16) split, packed pairwise into uints (elem k in low 16).
__device__ __forceinline__ void cvt2(float a, float b, unsigned& hp, unsigned& lp) {
  unsigned ua = __float_as_uint(a), ub = __float_as_uint(b);
  unsigned ha = (ua + 0x8000u) & 0xffff0000u;
  unsigned hb = (ub + 0x8000u) & 0xffff0000u;
  float la = a - __uint_as_float(ha);
  float lb = b - __uint_as_float(hb);
  hp = (ha >> 16) | hb;
  lp = (__float_as_uint(la) >> 16) | (__float_as_uint(lb) & 0xffff0000u);
}

union U8 { unsigned u[4]; short8 s; };

__global__ __launch_bounds__(256) void sentinel_kernel(float* __restrict__ out, int n, float v) {
  int i = blockIdx.x * 256 + threadIdx.x;
  if (i < n) out[i] = v;
}

// ---------------- BatchNorm stats ----------------
__global__ __launch_bounds__(256) void bn_stats_kernel(
    const float* __restrict__ tok, const float* __restrict__ g,
    const float* __restrict__ bb, float* __restrict__ ss) {
  __shared__ float red[256];
  const int d = blockIdx.x;
  float sum = 0.f, sumsq = 0.f;
  for (int s = threadIdx.x; s < 4096; s += 256) {
    float v = tok[s * 64 + d];
    sum += v; sumsq += v * v;
  }
  sum = block_reduce(sum, red);
  sumsq = block_reduce(sumsq, red);
  if (threadIdx.x == 0) {
    float mu = sum * (1.f / 4096.f);
    float var = sumsq * (1.f / 4096.f) - mu * mu;
    float sc = g[d] * rsqrtf(fmaxf(var, 0.f) + 1e-5f);
    ss[d] = sc;
    ss[64 + d] = bb[d] - mu * sc;
  }
}

__global__ __launch_bounds__(256) void tn_kernel(
    const float* __restrict__ tok, const float* __restrict__ ss,
    float* __restrict__ tn) {
  int idx = blockIdx.x * 256 + threadIdx.x;
  int d = idx & 63;
  tn[idx] = tok[idx] * ss[d] + ss[64 + d];
}

__global__ __launch_bounds__(256) void reverse_kernel(
    const float* __restrict__ x0, float* __restrict__ x0r) {
  int idx = blockIdx.x * 256 + threadIdx.x;
  int row = idx >> 9, e = idx & 511;
  int b = row >> 10, t = row & 1023;
  x0r[idx] = x0[((size_t)((b << 10) + (1023 - t))) * 512 + e];
}

// ---------------- row LayerNorm (N = 512 or 256) ----------------
__global__ __launch_bounds__(256) void ln_kernel(
    const float* __restrict__ x, const float* __restrict__ g,
    const float* __restrict__ b, float* __restrict__ out, int N) {
  __shared__ float red[256];
  const size_t r = blockIdx.x;
  const int tid = threadIdx.x;
  float v0 = x[r * N + tid];
  float v1 = (N > 256) ? x[r * N + 256 + tid] : 0.f;
  float sum = block_reduce(v0 + v1, red);
  float sumsq = block_reduce(v0 * v0 + v1 * v1, red);
  float mean = sum / (float)N;
  float var = sumsq / (float)N - mean * mean;
  float rs = rsqrtf(fmaxf(var, 0.f) + 1e-5f);
  out[r * N + tid] = (v0 - mean) * rs * g[tid] + b[tid];
  if (N > 256)
    out[r * N + 256 + tid] = (v1 - mean) * rs * g[256 + tid] + b[256 + tid];
}

// --------- small GEMM (f32): out[M,N] = A@W + bias (+resid)(act) ---------
#define BK 16
template <int ACT>  // 0 none, 1 gelu(exact), 2 tanh
__global__ __launch_bounds__(256) void gemm3(
    const float* __restrict__ A, const float* __restrict__ W,
    const float* __restrict__ bias, const float* resid,
    float* out, int M, int N, int K) {
  __shared__ float As[BK][64 + 4];
  __shared__ float Bs[BK][64 + 4];
  const int tid = threadIdx.x;
  const int tx = tid & 15, ty = tid >> 4;
  const int n0 = blockIdx.x * 64, m0 = blockIdx.y * 64;
  float acc[4][4] = {};
  for (int k0 = 0; k0 < K; k0 += BK) {
    {
      int m = tid >> 2, kq = tid & 3;
      float4 a4 = *reinterpret_cast<const float4*>(A + (size_t)(m0 + m) * K + k0 + kq * 4);
      As[kq * 4 + 0][m] = a4.x; As[kq * 4 + 1][m] = a4.y;
      As[kq * 4 + 2][m] = a4.z; As[kq * 4 + 3][m] = a4.w;
    }
    {
      int kk = tid >> 4, nq = tid & 15;
      float4 b4 = *reinterpret_cast<const float4*>(W + (size_t)(k0 + kk) * N + n0 + nq * 4);
      Bs[kk][nq * 4 + 0] = b4.x; Bs[kk][nq * 4 + 1] = b4.y;
      Bs[kk][nq * 4 + 2] = b4.z; Bs[kk][nq * 4 + 3] = b4.w;
    }
    __syncthreads();
#pragma unroll
    for (int kq = 0; kq < BK; ++kq) {
      float4 av = *reinterpret_cast<const float4*>(&As[kq][ty * 4]);
      float4 bv = *reinterpret_cast<const float4*>(&Bs[kq][tx * 4]);
      acc[0][0] += av.x * bv.x; acc[0][1] += av.x * bv.y; acc[0][2] += av.x * bv.z; acc[0][3] += av.x * bv.w;
      acc[1][0] += av.y * bv.x; acc[1][1] += av.y * bv.y; acc[1][2] += av.y * bv.z; acc[1][3] += av.y * bv.w;
      acc[2][0] += av.z * bv.x; acc[2][1] += av.z * bv.y; acc[2][2] += av.z * bv.z; acc[2][3] += av.z * bv.w;
      acc[3][0] += av.w * bv.x; acc[3][1] += av.w * bv.y; acc[3][2] += av.w * bv.z; acc[3][3] += av.w * bv.w;
    }
    __syncthreads();
  }
#pragma unroll
  for (int i = 0; i < 4; ++i) {
    int m = m0 + ty * 4 + i;
#pragma unroll
    for (int j = 0; j < 4; ++j) {
      int n = n0 + tx * 4 + j;
      float v = acc[i][j] + bias[n];
      if (resid) v += resid[(size_t)m * N + n];
      if (ACT == 1) v = 0.5f * v * (1.f + erff(v * 0.70710678118654752f));
      if (ACT == 2) v = tanhf(v);
      out[(size_t)m * N + n] = v;
    }
  }
}

// --------- MFMA GEMM, fp32 via bf16x3 split. 128x128x32 tiles, 4 waves. ---------
// 2-phase pipelined: tile t+1's global loads are issued into registers during
// tile t's MFMA phase (WAR on regs enforces ordering; compiler inserts vmcnt).
// XCD-aware swizzle: contiguous logical (x,y) chunks per XCD (all grids %8==0).
// ACT: 0 none, 1 gelu, 2 tanh. ATOMIC: atomicAdd into C (C pre-holds resid;
// z==0 adds bias). FUSE3: blockIdx.x selects one of 3 weight/bias/out sections.
template <int ACT, int ATOMIC, int FUSE3>
__global__ __launch_bounds__(256, 2) void gemm_mfma(
    const float* __restrict__ A,
    const float* __restrict__ B0, const float* __restrict__ B1, const float* __restrict__ B2,
    const float* __restrict__ bias0, const float* __restrict__ bias1, const float* __restrict__ bias2,
    const float* __restrict__ resid,
    float* __restrict__ C0, float* __restrict__ C1, float* __restrict__ C2,
    int M, int Nsec, int K, int KZ) {
  __shared__ unsigned Ah[128][20];
  __shared__ unsigned Al[128][20];
  __shared__ unsigned Bh[128][20];
  __shared__ unsigned Bl[128][20];
  const int tid = threadIdx.x;
  const int lane = tid & 63, wid = tid >> 6;
  const int wr = wid >> 1, wc = wid & 1;
  const int lr = lane & 15, lq = lane >> 4;

  // XCD swizzle over the (x,y) plane: hardware-consecutive ids round-robin
  // across 8 XCDs; remap so each XCD gets a contiguous logical chunk.
  const int gx = gridDim.x;
  int lin = blockIdx.y * gx + blockIdx.x;
  int qch = (gx * gridDim.y) >> 3;
  int swz = (lin & 7) * qch + (lin >> 3);
  int nb = swz % gx;
  const int mb = swz / gx;

  int sec = 0;
  if (FUSE3) { sec = nb >> 2; nb &= 3; }
  const float* Bg = FUSE3 ? (sec == 0 ? B0 : (sec == 1 ? B1 : B2)) : B0;
  const float* bias = FUSE3 ? (sec == 0 ? bias0 : (sec == 1 ? bias1 : bias2)) : bias0;
  float* C = FUSE3 ? (sec == 0 ? C0 : (sec == 1 ? C1 : C2)) : C0;
  const int n0 = nb * 128;
  const int m0 = mb * 128;
  const int kbase = blockIdx.z * KZ;
  const int kend = kbase + KZ;

  f32x4 acc[4][4];
#pragma unroll
  for (int i = 0; i < 4; ++i)
#pragma unroll
    for (int j = 0; j < 4; ++j) { acc[i][j][0] = 0.f; acc[i][j][1] = 0.f; acc[i][j][2] = 0.f; acc[i][j][3] = 0.f; }

  const int nB = tid & 127;
  const int khalf = tid >> 7;

  // ---- pipelined staging registers ----
  float4 a_reg[4];
  float b_reg[16];
  const int arow = tid >> 3, ac4 = tid & 7;  // this thread's A-load coords (i stride 32 rows)

  auto loadA = [&](int k0) {
#pragma unroll
    for (int i = 0; i < 4; ++i)
      a_reg[i] = *reinterpret_cast<const float4*>(
          A + (size_t)(m0 + arow + i * 32) * K + k0 + ac4 * 4);
  };
  auto loadB = [&](int k0) {
    const float* bp = Bg + (size_t)(k0 + khalf * 16) * Nsec + n0 + nB;
#pragma unroll
    for (int r = 0; r < 16; ++r) b_reg[r] = bp[(size_t)r * Nsec];
  };

  loadA(kbase);
  loadB(kbase);

  for (int k0 = kbase; k0 < kend; k0 += 32) {
    // ---- convert regs -> LDS (waits on the in-flight loads) ----
#pragma unroll
    for (int i = 0; i < 4; ++i) {
      int row = arow + i * 32;
      unsigned h0, l0, h1, l1;
      cvt2(a_reg[i].x, a_reg[i].y, h0, l0);
      cvt2(a_reg[i].z, a_reg[i].w, h1, l1);
      *reinterpret_cast<uint2*>(&Ah[row][ac4 * 2]) = make_uint2(h0, h1);
      *reinterpret_cast<uint2*>(&Al[row][ac4 * 2]) = make_uint2(l0, l1);
    }
    {
      unsigned hp[8], lp[8];
#pragma unroll
      for (int j = 0; j < 8; ++j) cvt2(b_reg[2 * j], b_reg[2 * j + 1], hp[j], lp[j]);
      int sw = nB & 3;
      int s0 = (khalf * 2) ^ sw, s1 = (khalf * 2 + 1) ^ sw;
      *reinterpret_cast<uint4*>(&Bh[nB][s0 * 4]) = make_uint4(hp[0], hp[1], hp[2], hp[3]);
      *reinterpret_cast<uint4*>(&Bh[nB][s1 * 4]) = make_uint4(hp[4], hp[5], hp[6], hp[7]);
      *reinterpret_cast<uint4*>(&Bl[nB][s0 * 4]) = make_uint4(lp[0], lp[1], lp[2], lp[3]);
      *reinterpret_cast<uint4*>(&Bl[nB][s1 * 4]) = make_uint4(lp[4], lp[5], lp[6], lp[7]);
    }
    __syncthreads();
    // ---- issue next tile's global loads (in flight across the MFMA phase) ----
    if (k0 + 32 < kend) { loadA(k0 + 32); loadB(k0 + 32); }
    // ---- fragments + 48 MFMA ----
    short8 ah[4], al[4], bh[4], bl[4];
#pragma unroll
    for (int mi = 0; mi < 4; ++mi) {
      int row = wr * 64 + mi * 16 + lr;
      ah[mi] = *reinterpret_cast<const short8*>(&Ah[row][lq * 4]);
      al[mi] = *reinterpret_cast<const short8*>(&Al[row][lq * 4]);
    }
#pragma unroll
    for (int ni = 0; ni < 4; ++ni) {
      int n = wc * 64 + ni * 16 + lr;
      int sp = lq ^ (n & 3);
      bh[ni] = *reinterpret_cast<const short8*>(&Bh[n][sp * 4]);
      bl[ni] = *reinterpret_cast<const short8*>(&Bl[n][sp * 4]);
    }
#pragma unroll
    for (int mi = 0; mi < 4; ++mi)
#pragma unroll
      for (int ni = 0; ni < 4; ++ni) {
        acc[mi][ni] = __builtin_amdgcn_mfma_f32_16x16x32_bf16(ah[mi], bh[ni], acc[mi][ni], 0, 0, 0);
        acc[mi][ni] = __builtin_amdgcn_mfma_f32_16x16x32_bf16(ah[mi], bl[ni], acc[mi][ni], 0, 0, 0);
        acc[mi][ni] = __builtin_amdgcn_mfma_f32_16x16x32_bf16(al[mi], bh[ni], acc[mi][ni], 0, 0, 0);
      }
    __syncthreads();
  }

#pragma unroll
  for (int mi = 0; mi < 4; ++mi) {
#pragma unroll
    for (int r = 0; r < 4; ++r) {
      int grow = m0 + wr * 64 + mi * 16 + lq * 4 + r;
#pragma unroll
      for (int ni = 0; ni < 4; ++ni) {
        int col = wc * 64 + ni * 16 + lr;
        float v = acc[mi][ni][r];
        if (ATOMIC) {
          if (blockIdx.z == 0) v += bias[n0 + col];
          atomicAdd(&C[(size_t)grow * Nsec + n0 + col], v);
        } else {
          v += bias[n0 + col];
          if (resid) v += resid[(size_t)grow * Nsec + n0 + col];
          if (ACT == 1) v = 0.5f * v * (1.f + erff(v * 0.70710678118654752f));
          if (ACT == 2) v = tanhf(v);
          C[(size_t)grow * Nsec + n0 + col] = v;
        }
      }
    }
  }
}

// ---------------- attention: MFMA flash, bf16x3, 64x64 tiles ----------------
__global__ __launch_bounds__(256, 2) void attn_mfma(
    const float* __restrict__ q, const float* __restrict__ k,
    const float* __restrict__ v, const float* __restrict__ mask,
    float* __restrict__ y, int rev) {
  __shared__ unsigned SH[4096];       // 16KB: Q staging, then V^T hi/lo
  __shared__ unsigned KhL[2048];      // 8KB  K hi
  __shared__ unsigned KlL[2048];      // 8KB  K lo
  __shared__ float PU[64 * 68];       // 17KB P (f32)
  __shared__ float km[64];
  unsigned* VhL = SH;
  unsigned* VlL = SH + 2048;

  const int tid = threadIdx.x;
  const int lane = tid & 63, w = tid >> 6;
  const int lr = lane & 15, lq = lane >> 4;

  const int id = blockIdx.x;          // complementary-pair mapping
  const int top = id >> 8;
  const int r5 = id & 255;
  const int qt = top ? (15 - (r5 >> 4)) : (r5 >> 4);
  const int bh_ = (r5 & 15) | (top << 4);
  const int b = bh_ >> 3, h = bh_ & 7;

  const size_t base = (size_t)(b * 1024) * 512 + h * 64;

  // ---- stage Q (scaled 1/8) into SH, swizzled ----
  {
    const float* qp = q + base + (size_t)(qt * 64) * 512;
    int row = tid >> 2, f4 = tid & 3;
#pragma unroll
    for (int j = 0; j < 4; ++j) {
      int dk = f4 * 4 + j * 16;
      float4 a = *reinterpret_cast<const float4*>(qp + (size_t)row * 512 + dk);
      unsigned h0, l0, h1, l1;
      cvt2(a.x * 0.125f, a.y * 0.125f, h0, l0);
      cvt2(a.z * 0.125f, a.w * 0.125f, h1, l1);
      int phys = (dk >> 3) ^ (row & 7);
      int off = row * 32 + phys * 4 + (f4 & 1) * 2;
      *reinterpret_cast<uint2*>(&SH[off]) = make_uint2(h0, h1);
      *reinterpret_cast<uint2*>(&KhL[off]) = make_uint2(l0, l1);  // temp: Q-lo in KhL
    }
  }
  __syncthreads();
  // preload Q A-fragments (row = w*16+lr)
  short8 qa_h[2], qa_l[2];
#pragma unroll
  for (int ks = 0; ks < 2; ++ks) {
    int row = w * 16 + lr;
    int phys = (lq + ks * 4) ^ (row & 7);
    qa_h[ks] = *reinterpret_cast<const short8*>(&SH[row * 32 + phys * 4]);
    qa_l[ks] = *reinterpret_cast<const short8*>(&KhL[row * 32 + phys * 4]);
  }
  __syncthreads();  // SH/KhL now free for V^T / K tiles

  float m_[4], l_[4] = {0.f, 0.f, 0.f, 0.f};
  f32x4 o_[4];
#pragma unroll
  for (int r = 0; r < 4; ++r) m_[r] = -1e30f;
#pragma unroll
  for (int df = 0; df < 4; ++df) { o_[df][0] = 0.f; o_[df][1] = 0.f; o_[df][2] = 0.f; o_[df][3] = 0.f; }

  for (int kt = 0; kt <= qt; ++kt) {
    const float* kp = k + base + (size_t)(kt * 64) * 512;
    const float* vp = v + base + (size_t)(kt * 64) * 512;
    // ---- stage K (row-major, swizzled) ----
    {
      int row = tid >> 2, f4 = tid & 3;
#pragma unroll
      for (int j = 0; j < 4; ++j) {
        int dk = f4 * 4 + j * 16;
        float4 a = *reinterpret_cast<const float4*>(kp + (size_t)row * 512 + dk);
        unsigned h0, l0, h1, l1;
        cvt2(a.x, a.y, h0, l0);
        cvt2(a.z, a.w, h1, l1);
        int phys = (dk >> 3) ^ (row & 7);
        int off = row * 32 + phys * 4 + (f4 & 1) * 2;
        *reinterpret_cast<uint2*>(&KhL[off]) = make_uint2(h0, h1);
        *reinterpret_cast<uint2*>(&KlL[off]) = make_uint2(l0, l1);
      }
    }
    // ---- stage V^T (key-pairs packed per uint, swizzled) ----
    {
      int d = tid & 63, g = tid >> 6;
#pragma unroll
      for (int j = 0; j < 8; ++j) {
        int kpair = (g + j * 4 + (d >> 3)) & 31;
        float v0 = vp[(size_t)(kpair * 2) * 512 + d];
        float v1 = vp[(size_t)(kpair * 2 + 1) * 512 + d];
        unsigned hh, ll;
        cvt2(v0, v1, hh, ll);
        int phys = (kpair >> 2) ^ (d & 7);
        int off = d * 32 + phys * 4 + (kpair & 3);
        VhL[off] = hh; VlL[off] = ll;
      }
    }
    if (tid < 64) {
      int s = kt * 64 + tid;
      km[tid] = mask[b * 1024 + (rev ? (1023 - s) : s)];
    }
    __syncthreads();

    // ---- S = Q K^T (x3 MFMA) ----
    f32x4 sacc[4];
#pragma unroll
    for (int kf = 0; kf < 4; ++kf) { sacc[kf][0] = 0.f; sacc[kf][1] = 0.f; sacc[kf][2] = 0.f; sacc[kf][3] = 0.f; }
#pragma unroll
    for (int ks = 0; ks < 2; ++ks) {
#pragma unroll
      for (int kf = 0; kf < 4; ++kf) {
        int col = kf * 16 + lr;
        int phys = (lq + ks * 4) ^ (lr & 7);
        short8 kbh = *reinterpret_cast<const short8*>(&KhL[col * 32 + phys * 4]);
        short8 kbl = *reinterpret_cast<const short8*>(&KlL[col * 32 + phys * 4]);
        sacc[kf] = __builtin_amdgcn_mfma_f32_16x16x32_bf16(qa_h[ks], kbh, sacc[kf], 0, 0, 0);
        sacc[kf] = __builtin_amdgcn_mfma_f32_16x16x32_bf16(qa_h[ks], kbl, sacc[kf], 0, 0, 0);
        sacc[kf] = __builtin_amdgcn_mfma_f32_16x16x32_bf16(qa_l[ks], kbh, sacc[kf], 0, 0, 0);
      }
    }

    // ---- online softmax in registers ----
    const bool diag = (kt == qt);
    float kmv[4];
#pragma unroll
    for (int kf = 0; kf < 4; ++kf) kmv[kf] = km[kf * 16 + lr];
#pragma unroll
    for (int r = 0; r < 4; ++r) {
      int fi = (w * 16 + lq * 4 + r) >> 3;
      float mt = -1e30f;
#pragma unroll
      for (int kf = 0; kf < 4; ++kf) {
        int key = kf * 16 + lr;
        bool ok = (kmv[kf] > 0.f) && (!diag || ((key >> 3) <= fi));
        float x = ok ? sacc[kf][r] : -1e30f;
        sacc[kf][r] = x;
        mt = fmaxf(mt, x);
      }
      mt = fmaxf(mt, __shfl_xor(mt, 1, 16));
      mt = fmaxf(mt, __shfl_xor(mt, 2, 16));
      mt = fmaxf(mt, __shfl_xor(mt, 4, 16));
      mt = fmaxf(mt, __shfl_xor(mt, 8, 16));
      float mn = fmaxf(m_[r], mt);
      float al = __expf(m_[r] - mn);
      m_[r] = mn;
      float rs = 0.f;
#pragma unroll
      for (int kf = 0; kf < 4; ++kf) {
        float sv = sacc[kf][r];
        float p = (sv > -1e29f) ? __expf(sv - mn) : 0.f;
        sacc[kf][r] = p;
        rs += p;
      }
      rs += __shfl_xor(rs, 1, 16);
      rs += __shfl_xor(rs, 2, 16);
      rs += __shfl_xor(rs, 4, 16);
      rs += __shfl_xor(rs, 8, 16);
      l_[r] = l_[r] * al + rs;
#pragma unroll
      for (int df = 0; df < 4; ++df) o_[df][r] *= al;
    }
    // ---- write P (f32, 68-stride) ----
#pragma unroll
    for (int kf = 0; kf < 4; ++kf)
#pragma unroll
      for (int r = 0; r < 4; ++r)
        PU[(w * 16 + lq * 4 + r) * 68 + kf * 16 + lr] = sacc[kf][r];
    __syncthreads();

    // ---- O += P V (x3 MFMA) ----
#pragma unroll
    for (int ks = 0; ks < 2; ++ks) {
      const float* pp = &PU[(w * 16 + lr) * 68 + ks * 32 + lq * 8];
      float4 p0 = *reinterpret_cast<const float4*>(pp);
      float4 p1 = *reinterpret_cast<const float4*>(pp + 4);
      U8 th, tl;
      cvt2(p0.x, p0.y, th.u[0], tl.u[0]);
      cvt2(p0.z, p0.w, th.u[1], tl.u[1]);
      cvt2(p1.x, p1.y, th.u[2], tl.u[2]);
      cvt2(p1.z, p1.w, th.u[3], tl.u[3]);
      short8 pa_h = th.s, pa_l = tl.s;
#pragma unroll
      for (int df = 0; df < 4; ++df) {
        int col = df * 16 + lr;
        int phys = (lq + ks * 4) ^ (lr & 7);
        short8 vbh = *reinterpret_cast<const short8*>(&VhL[col * 32 + phys * 4]);
        short8 vbl = *reinterpret_cast<const short8*>(&VlL[col * 32 + phys * 4]);
        o_[df] = __builtin_amdgcn_mfma_f32_16x16x32_bf16(pa_h, vbh, o_[df], 0, 0, 0);
        o_[df] = __builtin_amdgcn_mfma_f32_16x16x32_bf16(pa_h, vbl, o_[df], 0, 0, 0);
        o_[df] = __builtin_amdgcn_mfma_f32_16x16x32_bf16(pa_l, vbh, o_[df], 0, 0, 0);
      }
    }
    __syncthreads();
  }

  // ---- normalize + write ----
#pragma unroll
  for (int r = 0; r < 4; ++r) {
    float inv = 1.f / fmaxf(l_[r], 1e-30f);
    int qrow = qt * 64 + w * 16 + lq * 4 + r;
#pragma unroll
    for (int df = 0; df < 4; ++df)
      y[base + (size_t)qrow * 512 + df * 16 + lr] = o_[df][r] * inv;
  }
}

// ---------------- frame mean (+ FLOAT32 output write) ----------------
__global__ __launch_bounds__(256) void frame_mean_kernel(
    const float* __restrict__ xo, float* __restrict__ xf,
    float* __restrict__ outf) {
  int row = blockIdx.x;       // b*128+tf
  int o = threadIdx.x;
  float s = 0.f;
#pragma unroll
  for (int c = 0; c < 8; ++c) s += xo[((size_t)row * 8 + c) * 256 + o];
  s *= 0.125f;
  xf[row * 256 + o] = s;
  if (outf) outf[row * 256 + o] = s;
}

// ---------------- losses ----------------
__global__ __launch_bounds__(256) void loss_reg_kernel(
    const float* __restrict__ pd, const float* __restrict__ tok,
    const float* __restrict__ mask, float* __restrict__ acc, int rev) {
  __shared__ float red[256];
  float local = 0.f;
  for (int idx = blockIdx.x * 256 + threadIdx.x; idx < 260096; idx += gridDim.x * 256) {
    int b = idx / 65024, r2 = idx % 65024;
    int t = r2 >> 6, d = r2 & 63;
    float pred = pd[((size_t)((b << 10) + t)) * 64 + d] * mask[(b << 10) + t];
    int tt = rev ? (1015 - t) : (t + 8);
    float tgt = tok[((size_t)((b << 10) + tt)) * 64 + d] * mask[(b << 10) + tt];
    float df = pred - tgt;
    local += df * df;
  }
  float s = block_reduce(local, red);
  if (threadIdx.x == 0) atomicAdd(acc, s);
}

__global__ __launch_bounds__(256) void loss_fr_kernel(
    const float* __restrict__ pf, const float* __restrict__ tok,
    const float* __restrict__ mask, float* __restrict__ acc, int rev) {
  __shared__ float red[256];
  float local = 0.f;
  for (int idx = blockIdx.x * 256 + threadIdx.x; idx < 260096; idx += gridDim.x * 256) {
    int b = idx / 65024, r2 = idx % 65024;
    int i = r2 >> 9, u = r2 & 511;
    float pred = pf[((size_t)(b * 128 + i)) * 512 + u];
    int c = u >> 6;
    int t = rev ? ((126 - i) * 8 + c) : ((i + 1) * 8 + c);
    float tgt = tok[((size_t)((b << 10) + t)) * 64 + (u & 63)] * mask[(b << 10) + t];
    float df = pred - tgt;
    local += df * df;
  }
  float s = block_reduce(local, red);
  if (threadIdx.x == 0) atomicAdd(acc, s);
}

__global__ void finalize_kernel(const float* __restrict__ acc, float* __restrict__ out) {
  int i = threadIdx.x;
  if (i < 4) out[131072 + i] = acc[i] * (1.0f / 260096.0f);
}

extern "C" void kernel_launch(void* const* d_in, const int* in_sizes, int n_in,
                              void* d_out, int out_size, void* d_ws, size_t ws_size,
                              hipStream_t stream) {
  float* ws = (float*)d_ws;
  const size_t OFF_SS   = 0;
  const size_t OFF_LACC = 128;
  const size_t OFF_TN   = 256;
  const size_t OFF_X0   = OFF_TN + 262144;
  const size_t OFF_X0R  = OFF_X0 + 2097152;
  const size_t OFF_X    = OFF_X0R + 2097152;
  const size_t OFF_H    = OFF_X + 2097152;
  const size_t OFF_QKVY = OFF_H + 2097152;
  const size_t OFF_XO   = OFF_QKVY + 8388608;
  const size_t OFF_HD   = OFF_XO + 1048576;
  const size_t OFF_HD2  = OFF_HD + 1048576;
  const size_t OFF_PD   = OFF_HD2 + 1048576;
  const size_t OFF_XF   = OFF_PD + 262144;
  const size_t OFF_HF   = OFF_XF + 131072;
  const size_t OFF_HF2  = OFF_HF + 131072;
  const size_t OFF_PF   = OFF_HF2 + 131072;
  const size_t TOTAL    = OFF_PF + 262144;

  float* ss   = ws + OFF_SS;
  float* lacc = ws + OFF_LACC;
  float* tn   = ws + OFF_TN;
  float* x0   = ws + OFF_X0;
  float* x0r  = ws + OFF_X0R;
  float* x    = ws + OFF_X;
  float* h    = ws + OFF_H;
  float* q    = ws + OFF_QKVY;
  float* kk   = ws + OFF_QKVY + 2097152;
  float* vv   = ws + OFF_QKVY + 4194304;
  float* yb   = ws + OFF_QKVY + 6291456;
  float* u    = ws + OFF_QKVY;  // alias (MLP phase only)
  float* xo   = ws + OFF_XO;
  float* hd   = ws + OFF_HD;
  float* hd2  = ws + OFF_HD2;
  float* pd   = ws + OFF_PD;
  float* xf   = ws + OFF_XF;
  float* hf   = ws + OFF_HF;
  float* hf2  = ws + OFF_HF2;
  float* pf   = ws + OFF_PF;
  float* out_f = (float*)d_out;   // OUTPUT IS FLOAT32

  static const int EXPECTED[39] = {
      262144, 4096, 4096, 64, 64, 32768, 512, 3072, 3072, 3072, 3072,
      1572864, 3072, 1572864, 3072, 1572864, 3072, 1572864, 3072,
      6291456, 12288, 6291456, 3072, 512, 512, 131072, 256, 65536, 256,
      256, 256, 16384, 64, 65536, 256, 256, 256, 131072, 512};
  bool manifest_ok = (n_in == 39) && (ws_size >= TOTAL * sizeof(float));
  if (manifest_ok)
    for (int i = 0; i < 39; ++i)
      if (in_sizes[i] != EXPECTED[i]) { manifest_ok = false; break; }
  if (!manifest_ok) {
    hipLaunchKernelGGL(sentinel_kernel, dim3((out_size + 255) / 256), dim3(256), 0, stream,
                       out_f, out_size, 2000.0f);
    return;
  }

  const float* tok    = (const float*)d_in[0];
  const float* mask   = (const float*)d_in[2];
  const float* bn_g   = (const float*)d_in[3];
  const float* bn_b   = (const float*)d_in[4];
  const float* We     = (const float*)d_in[5];
  const float* be     = (const float*)d_in[6];
  const float* ln1_g  = (const float*)d_in[7];
  const float* ln1_b  = (const float*)d_in[8];
  const float* ln2_g  = (const float*)d_in[9];
  const float* ln2_b  = (const float*)d_in[10];
  const float* Wq     = (const float*)d_in[11];
  const float* bq     = (const float*)d_in[12];
  const float* Wk     = (const float*)d_in[13];
  const float* bk     = (const float*)d_in[14];
  const float* Wv     = (const float*)d_in[15];
  const float* bv     = (const float*)d_in[16];
  const float* Wo     = (const float*)d_in[17];
  const float* bo     = (const float*)d_in[18];
  const float* W1     = (const float*)d_in[19];
  const float* b1     = (const float*)d_in[20];
  const float* W2     = (const float*)d_in[21];
  const float* b2     = (const float*)d_in[22];
  const float* lnf_g  = (const float*)d_in[23];
  const float* lnf_b  = (const float*)d_in[24];
  const float* Wp     = (const float*)d_in[25];
  const float* bp     = (const float*)d_in[26];
  const float* Wd1    = (const float*)d_in[27];
  const float* bd1    = (const float*)d_in[28];
  const float* lnd_g  = (const float*)d_in[29];
  const float* lnd_b  = (const float*)d_in[30];
  const float* Wd2    = (const float*)d_in[31];
  const float* bd2    = (const float*)d_in[32];
  const float* Wf1    = (const float*)d_in[33];
  const float* bf1    = (const float*)d_in[34];
  const float* lnfr_g = (const float*)d_in[35];
  const float* lnfr_b = (const float*)d_in[36];
  const float* Wf2    = (const float*)d_in[37];
  const float* bf2    = (const float*)d_in[38];

  auto G = [&](int act, const float* A, const float* W, const float* bias,
               const float* resid, float* out, int M, int N, int K) {
    dim3 g(N / 64, M / 64), b(256);
    if (act == 0) hipLaunchKernelGGL((gemm3<0>), g, b, 0, stream, A, W, bias, resid, out, M, N, K);
    else if (act == 1) hipLaunchKernelGGL((gemm3<1>), g, b, 0, stream, A, W, bias, resid, out, M, N, K);
    else hipLaunchKernelGGL((gemm3<2>), g, b, 0, stream, A, W, bias, resid, out, M, N, K);
  };

  hipMemsetAsync(lacc, 0, 4 * sizeof(float), stream);
  hipLaunchKernelGGL(bn_stats_kernel, dim3(64), dim3(256), 0, stream, tok, bn_g, bn_b, ss);
  hipLaunchKernelGGL(tn_kernel, dim3(1024), dim3(256), 0, stream, tok, ss, tn);
  G(0, tn, We, be, nullptr, x0, 4096, 512, 64);
  hipLaunchKernelGGL(reverse_kernel, dim3(8192), dim3(256), 0, stream, x0, x0r);

  for (int dir = 0; dir < 2; ++dir) {
    const float* xin = dir ? x0r : x0;
    for (int l = 0; l < 6; ++l) {
      const float* xl = (l == 0) ? xin : x;
      hipLaunchKernelGGL(ln_kernel, dim3(4096), dim3(256), 0, stream,
                         xl, ln1_g + l * 512, ln1_b + l * 512, h, 512);
      // fused QKV (N=3*512), MFMA bf16x3
      hipLaunchKernelGGL((gemm_mfma<0, 0, 1>), dim3(12, 32, 1), dim3(256), 0, stream,
                         h, Wq + (size_t)l * 262144, Wk + (size_t)l * 262144, Wv + (size_t)l * 262144,
                         bq + l * 512, bk + l * 512, bv + l * 512, nullptr,
                         q, kk, vv, 4096, 512, 512, 512);
      // seed x with the residual for layer 0 (for l>0, x already holds xl)
      if (l == 0)
        hipMemcpyAsync(x, xin, 2097152 * sizeof(float), hipMemcpyDeviceToDevice, stream);
      hipLaunchKernelGGL(attn_mfma, dim3(512), dim3(256), 0, stream,
                         q, kk, vv, mask, yb, dir);
      // O-proj: split-K=2, atomicAdd into x (x pre-holds residual)
      hipLaunchKernelGGL((gemm_mfma<0, 1, 0>), dim3(4, 32, 2), dim3(256), 0, stream,
                         yb, Wo + (size_t)l * 262144, nullptr, nullptr,
                         bo + l * 512, nullptr, nullptr, nullptr,
                         x, nullptr, nullptr, 4096, 512, 512, 256);
      hipLaunchKernelGGL(ln_kernel, dim3(4096), dim3(256), 0, stream,
                         x, ln2_g + l * 512, ln2_b + l * 512, h, 512);
      // MLP up + gelu
      hipLaunchKernelGGL((gemm_mfma<1, 0, 0>), dim3(16, 32, 1), dim3(256), 0, stream,
                         h, W1 + (size_t)l * 1048576, nullptr, nullptr,
                         b1 + l * 2048, nullptr, nullptr, nullptr,
                         u, nullptr, nullptr, 4096, 2048, 512, 512);
      // MLP down: split-K=2, atomicAdd into x (x already holds residual)
      hipLaunchKernelGGL((gemm_mfma<0, 1, 0>), dim3(4, 32, 2), dim3(256), 0, stream,
                         u, W2 + (size_t)l * 1048576, nullptr, nullptr,
                         b2 + l * 512, nullptr, nullptr, nullptr,
                         x, nullptr, nullptr, 4096, 512, 2048, 1024);
    }
    hipLaunchKernelGGL(ln_kernel, dim3(4096), dim3(256), 0, stream, x, lnf_g, lnf_b, h, 512);
    // head projection + decoder first layer on MFMA (N=256)
    hipLaunchKernelGGL((gemm_mfma<0, 0, 0>), dim3(2, 32, 1), dim3(256), 0, stream,
                       h, Wp, nullptr, nullptr, bp, nullptr, nullptr, nullptr,
                       xo, nullptr, nullptr, 4096, 256, 512, 512);
    hipLaunchKernelGGL((gemm_mfma<2, 0, 0>), dim3(2, 32, 1), dim3(256), 0, stream,
                       xo, Wd1, nullptr, nullptr, bd1, nullptr, nullptr, nullptr,
                       hd, nullptr, nullptr, 4096, 256, 256, 256);
    hipLaunchKernelGGL(ln_kernel, dim3(4096), dim3(256), 0, stream, hd, lnd_g, lnd_b, hd2, 256);
    G(0, hd2, Wd2, bd2, nullptr, pd, 4096, 64, 256);
    hipLaunchKernelGGL(loss_reg_kernel, dim3(256), dim3(256), 0, stream,
                       pd, tok, mask, lacc + (dir ? 1 : 0), dir);
    hipLaunchKernelGGL(frame_mean_kernel, dim3(512), dim3(256), 0, stream,
                       xo, xf, dir == 0 ? out_f : (float*)nullptr);
    G(2, xf, Wf1, bf1, nullptr, hf, 512, 256, 256);
    hipLaunchKernelGGL(ln_kernel, dim3(512), dim3(256), 0, stream, hf, lnfr_g, lnfr_b, hf2, 256);
    G(0, hf2, Wf2, bf2, nullptr, pf, 512, 512, 256);
    hipLaunchKernelGGL(loss_fr_kernel, dim3(256), dim3(256), 0, stream,
                       pf, tok, mask, lacc + (dir ? 3 : 2), dir);
  }
  hipLaunchKernelGGL(finalize_kernel, dim3(1), dim3(64), 0, stream, lacc, out_f);
}